// Round 9
// baseline (3334.080 us; speedup 1.0000x reference)
//
#include <hip/hip_runtime.h>

typedef unsigned short u16;
typedef unsigned int u32;

#define NN 50000
#define NE 800000
#define FD 96

typedef float f32x4 __attribute__((ext_vector_type(4)));
typedef __bf16 bf16x8 __attribute__((ext_vector_type(8)));
typedef u16 u16x8 __attribute__((ext_vector_type(8)));
typedef u16 u16x4 __attribute__((ext_vector_type(4)));

__device__ __forceinline__ float bf2f(u16 u) { return __uint_as_float(((u32)u) << 16); }
__device__ __forceinline__ u16 f2bf(float f) {
  u32 u = __float_as_uint(f);
  u += 0x7fffu + ((u >> 16) & 1u);   // round-to-nearest-even
  return (u16)(u >> 16);
}

__device__ __forceinline__ f32x4 MFMA(u16x8 a, u16x8 b, f32x4 c) {
  return __builtin_amdgcn_mfma_f32_16x16x32_bf16(
      __builtin_bit_cast(bf16x8, a), __builtin_bit_cast(bf16x8, b), c, 0, 0, 0);
}

// ---------------- weight prep: fp32 -> bf16, transposed [n][k] blocks ----------------
// 6 blocks: 0 ew1[96:192] (proj send), 1 ew1[192:288] (proj recv),
//           2 nw1[0:96], 3 nw1[96:192], 4 nw1[192:288], 5 nw2
__global__ void gn_wprep(const float* __restrict__ ew1,
                         const float* __restrict__ nw1, const float* __restrict__ nw2,
                         u16* __restrict__ wt) {
  int gid = blockIdx.x * 256 + threadIdx.x;
  if (gid >= 6 * 3 * 9216) return;
  int b = gid / (3 * 9216);
  int rem = gid - b * 3 * 9216;
  int s = rem / 9216;
  int e = rem - s * 9216;
  int n = e / 96, k = e - n * 96;
  float v;
  switch (b) {
    case 0: v = ew1[s * 36864 + (96 + k) * 96 + n]; break;
    case 1: v = ew1[s * 36864 + (192 + k) * 96 + n]; break;
    case 2: v = nw1[s * 36864 + k * 96 + n]; break;
    case 3: v = nw1[s * 36864 + (96 + k) * 96 + n]; break;
    case 4: v = nw1[s * 36864 + (192 + k) * 96 + n]; break;
    default: v = nw2[s * 9216 + k * 96 + n]; break;
  }
  wt[gid] = f2bf(v);
}

// ---------------- fragment-major weight prep for edge kernel ----------------
__global__ void gn_wprep_frag(const float* __restrict__ ew1, const float* __restrict__ ew2,
                              u16* __restrict__ wf) {
  int gid = blockIdx.x * 256 + threadIdx.x;
  if (gid >= 2 * 3 * 9216) return;
  int b = gid / (3 * 9216);
  int rem = gid - b * 3 * 9216;
  int s = rem / 9216;
  int idx = rem - s * 9216;
  int j = idx & 7, lane = (idx >> 3) & 63, tkb = idx >> 9;
  int kb = tkb % 3, t = tkb / 3;
  int k = kb * 32 + (lane >> 4) * 8 + j;
  int n = t * 16 + (lane & 15);
  float v = (b == 0) ? ew1[s * 36864 + k * 96 + n] : ew2[s * 9216 + k * 96 + n];
  wf[gid] = f2bf(v);
}

// ---------------- embedders (MFMA, transposed-C) ----------------
__global__ __launch_bounds__(256) void gn_embed_e_mfma(
    const float* __restrict__ edges, const float* __restrict__ W,
    const float* __restrict__ b, const int* __restrict__ pos_s,
    u16* __restrict__ out) {
  __shared__ u16 WS[96][40];
  for (int i = threadIdx.x; i < 96 * 32; i += 256) {
    int n = i >> 5, k = i & 31;
    WS[n][k] = (k < 16) ? f2bf(W[k * 96 + n]) : (u16)0;
  }
  __syncthreads();
  const int wave = threadIdx.x >> 6, lane = threadIdx.x & 63;
  const int l15 = lane & 15, lhi = lane >> 4;
  #pragma unroll 1
  for (int grp = 0; grp < 2; grp++) {
    const long ec = (long)blockIdx.x * 128 + (wave * 2 + grp) * 16 + l15;
    const long dst = pos_s[ec];
    u16x8 xf = {0, 0, 0, 0, 0, 0, 0, 0};
    if (lhi < 2) {
      const float* er = edges + ec * 16 + lhi * 8;
      f32x4 e0 = *(const f32x4*)er;
      f32x4 e1 = *(const f32x4*)(er + 4);
      xf = (u16x8){f2bf(e0[0]), f2bf(e0[1]), f2bf(e0[2]), f2bf(e0[3]),
                   f2bf(e1[0]), f2bf(e1[1]), f2bf(e1[2]), f2bf(e1[3])};
    }
    #pragma unroll
    for (int t = 0; t < 6; t++) {
      u16x8 wf = *(const u16x8*)&WS[t * 16 + l15][lhi * 8];
      f32x4 acc = {};
      acc = MFMA(wf, xf, acc);
      f32x4 bv = *(const f32x4*)(b + t * 16 + lhi * 4);
      f32x4 ov = acc + bv;
      u16x4 r = {f2bf(ov[0]), f2bf(ov[1]), f2bf(ov[2]), f2bf(ov[3])};
      *(u16x4*)(out + dst * 96 + t * 16 + lhi * 4) = r;
    }
  }
}

__global__ __launch_bounds__(256) void gn_embed_n_mfma(
    const float* __restrict__ nodes, const float* __restrict__ W,
    const float* __restrict__ b, u16* __restrict__ out) {
  __shared__ u16 WS[96][40];
  for (int i = threadIdx.x; i < 96 * 32; i += 256) {
    int n = i >> 5, k = i & 31;
    WS[n][k] = f2bf(W[k * 96 + n]);
  }
  __syncthreads();
  const int wave = threadIdx.x >> 6, lane = threadIdx.x & 63;
  const int l15 = lane & 15, lhi = lane >> 4;
  #pragma unroll 1
  for (int grp = 0; grp < 2; grp++) {
    const int ncol = blockIdx.x * 128 + (wave * 2 + grp) * 16 + l15;
    const int nc = ncol < NN ? ncol : (NN - 1);
    const float* nr = nodes + (size_t)nc * 32 + lhi * 8;
    f32x4 e0 = *(const f32x4*)nr;
    f32x4 e1 = *(const f32x4*)(nr + 4);
    u16x8 xf = {f2bf(e0[0]), f2bf(e0[1]), f2bf(e0[2]), f2bf(e0[3]),
                f2bf(e1[0]), f2bf(e1[1]), f2bf(e1[2]), f2bf(e1[3])};
    if (ncol < NN) {
      #pragma unroll
      for (int t = 0; t < 6; t++) {
        u16x8 wf = *(const u16x8*)&WS[t * 16 + l15][lhi * 8];
        f32x4 acc = {};
        acc = MFMA(wf, xf, acc);
        f32x4 bv = *(const f32x4*)(b + t * 16 + lhi * 4);
        f32x4 ov = acc + bv;
        u16x4 r = {f2bf(ov[0]), f2bf(ov[1]), f2bf(ov[2]), f2bf(ov[3])};
        *(u16x4*)(out + (size_t)ncol * 96 + t * 16 + lhi * 4) = r;
      }
    }
  }
}

__global__ void gn_gembed(const float* __restrict__ g_in, const float* __restrict__ W,
                          const float* __restrict__ b, float* __restrict__ gbuf) {
  int f = threadIdx.x;
  if (f >= 96) return;
  float a = b[f];
  #pragma unroll
  for (int k = 0; k < 8; k++) a += g_in[k] * W[k * 96 + f];
  gbuf[f] = a;
}

// ---------------- CSR build ----------------
__global__ void gn_hist(const int* __restrict__ snd, const int* __restrict__ rcv,
                        int* __restrict__ cs, int* __restrict__ cr) {
  int i = blockIdx.x * 256 + threadIdx.x;
  if (i >= NE) return;
  atomicAdd(&cs[snd[i]], 1);
  atomicAdd(&cr[rcv[i]], 1);
}

__global__ void gn_scan(const int* cnt, int* row_ptr, int* cursor, int n) {
  __shared__ int lsum[1024];
  int t = threadIdx.x;
  int chunk = (n + 1023) >> 10;
  int s0 = t * chunk;
  int s1 = s0 + chunk; if (s1 > n) s1 = n;
  int s = 0;
  for (int i = s0; i < s1; i++) s += cnt[i];
  lsum[t] = s;
  __syncthreads();
  for (int off = 1; off < 1024; off <<= 1) {
    int v = (t >= off) ? lsum[t - off] : 0;
    __syncthreads();
    lsum[t] += v;
    __syncthreads();
  }
  if (t == 0) row_ptr[n] = lsum[1023];
  int prefix = (t == 0) ? 0 : lsum[t - 1];
  for (int i = s0; i < s1; i++) {
    int c = cnt[i];
    row_ptr[i] = prefix;
    cursor[i] = prefix;
    prefix += c;
  }
}

// scatter2: build sorted-space metadata.
__global__ void gn_scatter2(const int* __restrict__ snd, const int* __restrict__ rcv,
                            int* cur_s, int* cur_r,
                            int* __restrict__ el_s, int* __restrict__ pos_s,
                            int* __restrict__ el_r2,
                            int* __restrict__ snd_srt, int* __restrict__ rcv_srt) {
  int i = blockIdx.x * 256 + threadIdx.x;
  if (i >= NE) return;
  int s = snd[i], r = rcv[i];
  int p = atomicAdd(&cur_s[s], 1);
  int q = atomicAdd(&cur_r[r], 1);
  el_s[p] = i;
  pos_s[i] = p;
  el_r2[q] = p;
  snd_srt[p] = s;
  rcv_srt[p] = r;
}

// ---------------- column sums ----------------
__global__ void gn_colsum(const u16* __restrict__ x, float* __restrict__ out, int M) {
  int w = threadIdx.x & 63;
  int rg = threadIdx.x >> 6;
  if (w >= 48) return;
  float ax = 0.f, ay = 0.f;
  for (int r = blockIdx.x * 4 + rg; r < M; r += gridDim.x * 4) {
    u32 v = ((const u32*)(x + (size_t)r * 96))[w];
    ax += bf2f((u16)(v & 0xffffu));
    ay += bf2f((u16)(v >> 16));
  }
  atomicAdd(&out[2 * w], ax);
  atomicAdd(&out[2 * w + 1], ay);
}

__global__ void gn_colsum32(const float* __restrict__ x, float* __restrict__ out, int M) {
  int w = threadIdx.x & 63;
  int rg = threadIdx.x >> 6;
  if (w >= 48) return;
  float ax = 0.f, ay = 0.f;
  for (int r = blockIdx.x * 4 + rg; r < M; r += gridDim.x * 4) {
    const float* row = x + (size_t)r * 96 + w * 2;
    ax += row[0];
    ay += row[1];
  }
  atomicAdd(&out[2 * w], ax);
  atomicAdd(&out[2 * w + 1], ay);
}

// ---------------- per-step constant vectors: cvec = g @ W_gblock + b1 ----------------
__global__ void gn_cvec(const float* __restrict__ g, const float* __restrict__ ew1,
                        const float* __restrict__ eb1, float* __restrict__ cve,
                        const float* __restrict__ nw1, const float* __restrict__ nb1,
                        float* __restrict__ cvn, int s) {
  int f = threadIdx.x;
  if (f >= 96) return;
  const float* W = (blockIdx.x == 0 ? ew1 : nw1) + s * 36864 + 288 * 96;
  const float* b = (blockIdx.x == 0 ? eb1 : nb1) + s * 96;
  float* o = blockIdx.x == 0 ? cve : cvn;
  float a = b[f];
  for (int k = 0; k < 96; k++) a += g[k] * W[k * 96 + f];
  o[f] = a;
}

// ---------------- node projections: ps = n@ew1[96:192], pr = n@ew1[192:288] ----------------
__global__ __launch_bounds__(256) void gn_proj(const u16* __restrict__ n_in,
                                               const u16* __restrict__ wts, const u16* __restrict__ wtr,
                                               u16* __restrict__ ps, u16* __restrict__ pr) {
  __shared__ u16 WS[96][104];
  __shared__ u16 WR[96][104];
  for (int i = threadIdx.x; i < 96 * 48; i += 256) {
    int n = i / 48, k2 = (i - n * 48) * 2;
    *(u32*)&WS[n][k2] = ((const u32*)wts)[i];
    *(u32*)&WR[n][k2] = ((const u32*)wtr)[i];
  }
  __syncthreads();
  const int wave = threadIdx.x >> 6, lane = threadIdx.x & 63;
  const int l15 = lane & 15, lhi = lane >> 4;
  #pragma unroll 1
  for (int grp = 0; grp < 2; grp++) {
    const int gidx = wave * 2 + grp;
    const int ncol = blockIdx.x * 128 + gidx * 16 + l15;
    const int nc = ncol < NN ? ncol : (NN - 1);
    const u16* row = n_in + (size_t)nc * 96;
    u16x8 xf0 = *(const u16x8*)(row + 0 * 32 + lhi * 8);
    u16x8 xf1 = *(const u16x8*)(row + 1 * 32 + lhi * 8);
    u16x8 xf2 = *(const u16x8*)(row + 2 * 32 + lhi * 8);
    f32x4 a[6] = {}, b[6] = {};
    #pragma unroll
    for (int kb = 0; kb < 3; kb++) {
      u16x8 xf = (kb == 0) ? xf0 : ((kb == 1) ? xf1 : xf2);
      #pragma unroll
      for (int t = 0; t < 6; t++) {
        u16x8 wfa = *(const u16x8*)&WS[t * 16 + l15][kb * 32 + lhi * 8];
        u16x8 wfb = *(const u16x8*)&WR[t * 16 + l15][kb * 32 + lhi * 8];
        a[t] = MFMA(wfa, xf, a[t]);
        b[t] = MFMA(wfb, xf, b[t]);
      }
    }
    if (ncol < NN) {
      #pragma unroll
      for (int t = 0; t < 6; t++) {
        u16x4 ra = {f2bf(a[t][0]), f2bf(a[t][1]), f2bf(a[t][2]), f2bf(a[t][3])};
        u16x4 rb = {f2bf(b[t][0]), f2bf(b[t][1]), f2bf(b[t][2]), f2bf(b[t][3])};
        *(u16x4*)(ps + (size_t)ncol * 96 + t * 16 + lhi * 4) = ra;
        *(u16x4*)(pr + (size_t)ncol * 96 + t * 16 + lhi * 4) = rb;
      }
    }
  }
}

// ---------------- edge MLP v4: 4-wave blocks, W2 from global, fused send+recv segsum ----------------
#define ETPW 2
#define SB_P 104   // staged row pitch in u16 (208 B, 16-B aligned)
__global__ __launch_bounds__(256, 5) void gn_edge4(
    u16* __restrict__ e_st,
    const u16* __restrict__ ps, const u16* __restrict__ pr,
    const int* __restrict__ snd, const int* __restrict__ rcv,   // sorted-space
    const int* __restrict__ el_s,                               // sorted pos -> orig edge
    const float* __restrict__ cvec, const float* __restrict__ b2,
    const u16* __restrict__ wf1, const u16* __restrict__ wf2,   // wf2 consumed from global (L1-hot)
    float* __restrict__ sent32, float* __restrict__ recv32,
    float* __restrict__ out32) {
  __shared__ u16 W1[1152 * 8];     // fragment-major
  __shared__ u16 Hb[4][16 * SB_P]; // per-wave scratch: H-frag region + staged tile (time-shared)
  for (int i = threadIdx.x; i < 1152; i += 256)
    *(u16x8*)&W1[i * 8] = *(const u16x8*)(wf1 + (size_t)i * 8);
  __syncthreads();
  const int wave = threadIdx.x >> 6, lane = threadIdx.x & 63;
  const int l15 = lane & 15, lhi = lane >> 4;
  u16* myH = Hb[wave];
  const long t0 = ((long)blockIdx.x * 4 + wave) * ETPW;

  int r3[3], o3[3];
  #pragma unroll
  for (int s3 = 0; s3 < 3; s3++) { int g = s3 * 512 + lane * 8; r3[s3] = g / 96; o3[s3] = g - 96 * r3[s3]; }
  int r6[6], o6[6];
  #pragma unroll
  for (int s6 = 0; s6 < 6; s6++) { int g = s6 * 256 + lane * 4; r6[s6] = g / 96; o6[s6] = g - 96 * r6[s6]; }

  float ax = 0.f, ay = 0.f;   // sender-run accumulators (lanes<48)

  u16x8 xf0, xf1, xf2;
  u16x4 ga[6], gb[6];
  u16x8 nxf0, nxf1, nxf2; int nsi = 0, nri = 0;
  u16x4 nga[6], ngb[6];

  {
    const u16* erow = e_st + (t0 * 16 + l15) * 96;
    xf0 = *(const u16x8*)(erow + lhi * 8);
    xf1 = *(const u16x8*)(erow + 32 + lhi * 8);
    xf2 = *(const u16x8*)(erow + 64 + lhi * 8);
    int si = snd[t0 * 16 + l15], ri = rcv[t0 * 16 + l15];
    const u16* pa = ps + (size_t)si * 96 + lhi * 4;
    const u16* pb = pr + (size_t)ri * 96 + lhi * 4;
    #pragma unroll
    for (int t = 0; t < 6; t++) { ga[t] = *(const u16x4*)(pa + t * 16); gb[t] = *(const u16x4*)(pb + t * 16); }
  }

  #pragma unroll 1
  for (int it = 0; it < ETPW; it++) {
    const long tb = (t0 + it) * 16;            // first edge pos of tile
    const long ecol = tb + l15;
    if (it + 1 < ETPW) {
      const u16* erow = e_st + (ecol + 16) * 96;
      nxf0 = *(const u16x8*)(erow + lhi * 8);
      nxf1 = *(const u16x8*)(erow + 32 + lhi * 8);
      nxf2 = *(const u16x8*)(erow + 64 + lhi * 8);
      nsi = snd[ecol + 16]; nri = rcv[ecol + 16];
    }
    // GEMM1 (W1 from LDS)
    f32x4 acc[6] = {};
    #pragma unroll
    for (int t = 0; t < 6; t++) acc[t] = MFMA(*(const u16x8*)&W1[((t * 3 + 0) * 64 + lane) * 8], xf0, acc[t]);
    #pragma unroll
    for (int t = 0; t < 6; t++) acc[t] = MFMA(*(const u16x8*)&W1[((t * 3 + 1) * 64 + lane) * 8], xf1, acc[t]);
    #pragma unroll
    for (int t = 0; t < 6; t++) acc[t] = MFMA(*(const u16x8*)&W1[((t * 3 + 2) * 64 + lane) * 8], xf2, acc[t]);
    if (it + 1 < ETPW) {
      const u16* pa = ps + (size_t)nsi * 96 + lhi * 4;
      const u16* pb = pr + (size_t)nri * 96 + lhi * 4;
      #pragma unroll
      for (int t = 0; t < 6; t++) { nga[t] = *(const u16x4*)(pa + t * 16); ngb[t] = *(const u16x4*)(pb + t * 16); }
    }
    // guard: previous iteration's staged reads done before H-frag rewrite
    asm volatile("s_waitcnt lgkmcnt(0)" ::: "memory");
    __builtin_amdgcn_sched_barrier(0);
    // epilogue 1: add gathers + cvec, leaky-relu, write H fragment-major
    #pragma unroll
    for (int t = 0; t < 6; t++) {
      f32x4 cv = *(const f32x4*)(cvec + t * 16 + lhi * 4);
      u16x4 hp;
      #pragma unroll
      for (int j = 0; j < 4; j++) {
        float v = acc[t][j] + bf2f(ga[t][j]) + bf2f(gb[t][j]) + cv[j];
        v = v > 0.f ? v : 0.01f * v;
        hp[j] = f2bf(v);
      }
      int q = (4 * t + lhi) & 7;
      int kb2 = (4 * t + lhi) >> 3;
      *(u16x4*)&myH[(kb2 * 64 + (q >> 1) * 16 + l15) * 8 + (q & 1) * 4] = hp;
    }
    // GEMM2 (W2 from global; 1 KB/wave coalesced, L1-resident)
    f32x4 o[6] = {};
    #pragma unroll
    for (int kb = 0; kb < 3; kb++) {
      u16x8 hf = *(const u16x8*)&myH[(kb * 64 + lane) * 8];
      #pragma unroll
      for (int t = 0; t < 6; t++)
        o[t] = MFMA(*(const u16x8*)(wf2 + ((size_t)(t * 3 + kb) * 64 + lane) * 8), hf, o[t]);
    }
    // stage bf16 tile [16][SB_P]
    asm volatile("s_waitcnt lgkmcnt(0)" ::: "memory");
    __builtin_amdgcn_sched_barrier(0);
    #pragma unroll
    for (int t = 0; t < 6; t++) {
      f32x4 bv = *(const f32x4*)(b2 + t * 16 + lhi * 4);
      f32x4 ov = o[t] + bv;
      u16x4 r4 = {f2bf(ov[0]), f2bf(ov[1]), f2bf(ov[2]), f2bf(ov[3])};
      *(u16x4*)&myH[l15 * SB_P + t * 16 + lhi * 4] = r4;
    }
    asm volatile("s_waitcnt lgkmcnt(0)" ::: "memory");
    __builtin_amdgcn_sched_barrier(0);
    // coalesced e_st store: 3 x 1KB contiguous bursts
    #pragma unroll
    for (int s3 = 0; s3 < 3; s3++) {
      u16x8 v = *(const u16x8*)&myH[r3[s3] * SB_P + o3[s3]];
      *(u16x8*)(e_st + tb * 96 + s3 * 512 + lane * 8) = v;
    }
    // out32 (last step): scatter rows to original edge order
    if (out32) {
      #pragma unroll
      for (int s6 = 0; s6 < 6; s6++) {
        long oc = el_s[tb + r6[s6]];
        u16x4 v = *(const u16x4*)&myH[r6[s6] * SB_P + o6[s6]];
        f32x4 f = {bf2f(v[0]), bf2f(v[1]), bf2f(v[2]), bf2f(v[3])};
        *(f32x4*)(out32 + oc * 96 + o6[s6]) = f;
      }
    }
    // fused segsum: sender run-batched + receiver coalesced row atomics
    if (lane < 48) {
      #pragma unroll
      for (int r = 0; r < 16; r++) {
        u32 v = *(const u32*)&myH[r * SB_P + lane * 2];
        float lo = bf2f((u16)(v & 0xffffu)), hi = bf2f((u16)(v >> 16));
        // receiver side: lanes 0..47 hit 192 consecutive bytes of row rcv[tb+r]
        int rcur = rcv[tb + r];
        atomicAdd(&recv32[(size_t)rcur * 96 + lane * 2], lo);
        atomicAdd(&recv32[(size_t)rcur * 96 + lane * 2 + 1], hi);
        // sender side: run-batched (sorted)
        ax += lo; ay += hi;
        int scur = snd[tb + r];
        bool flush;
        if (r < 15) flush = (snd[tb + r + 1] != scur);
        else flush = (it == ETPW - 1) || (snd[tb + 16] != scur);
        if (flush) {
          atomicAdd(&sent32[(size_t)scur * 96 + lane * 2], ax);
          atomicAdd(&sent32[(size_t)scur * 96 + lane * 2 + 1], ay);
          ax = 0.f; ay = 0.f;
        }
      }
    }
    xf0 = nxf0; xf1 = nxf1; xf2 = nxf2;
    #pragma unroll
    for (int t = 0; t < 6; t++) { ga[t] = nga[t]; gb[t] = ngb[t]; }
  }
}

// ---------------- node MLP (K=288; sent and recv read as f32) ----------------
__global__ __launch_bounds__(256) void gn_node(
    const u16* __restrict__ n_in, const float* __restrict__ sent32, const float* __restrict__ recv32,
    const u16* __restrict__ wta, const u16* __restrict__ wtb, const u16* __restrict__ wtc,
    const u16* __restrict__ wt2,
    const float* __restrict__ cvec, const float* __restrict__ b2,
    u16* __restrict__ n_out, float* __restrict__ out32) {
  __shared__ u16 WA[96][104];
  __shared__ u16 WB[96][104];
  __shared__ u16 Hb[4][16][104];
  for (int i = threadIdx.x; i < 96 * 48; i += 256) {
    int n = i / 48, k2 = (i - n * 48) * 2;
    *(u32*)&WA[n][k2] = ((const u32*)wta)[i];
    *(u32*)&WB[n][k2] = ((const u32*)wtb)[i];
  }
  __syncthreads();
  const int wave = threadIdx.x >> 6, lane = threadIdx.x & 63;
  const int l15 = lane & 15, lhi = lane >> 4;
  #pragma unroll 1
  for (int grp = 0; grp < 2; grp++) {
    const int gidx = wave * 2 + grp;
    const int ncol = blockIdx.x * 128 + gidx * 16 + l15;
    const int nc = ncol < NN ? ncol : (NN - 1);
    f32x4 acc[6] = {};
    {
      const u16* row = n_in + (size_t)nc * 96;
      #pragma unroll
      for (int kb = 0; kb < 3; kb++) {
        u16x8 xf = *(const u16x8*)(row + kb * 32 + lhi * 8);
        #pragma unroll
        for (int t = 0; t < 6; t++) {
          u16x8 wf = *(const u16x8*)&WA[t * 16 + l15][kb * 32 + lhi * 8];
          acc[t] = MFMA(wf, xf, acc[t]);
        }
      }
    }
    {
      const float* srow = sent32 + (size_t)nc * 96;
      #pragma unroll
      for (int kb = 0; kb < 3; kb++) {
        f32x4 a0 = *(const f32x4*)(srow + kb * 32 + lhi * 8);
        f32x4 a1 = *(const f32x4*)(srow + kb * 32 + lhi * 8 + 4);
        u16x8 xf = {f2bf(a0[0]), f2bf(a0[1]), f2bf(a0[2]), f2bf(a0[3]),
                    f2bf(a1[0]), f2bf(a1[1]), f2bf(a1[2]), f2bf(a1[3])};
        #pragma unroll
        for (int t = 0; t < 6; t++) {
          u16x8 wf = *(const u16x8*)&WB[t * 16 + l15][kb * 32 + lhi * 8];
          acc[t] = MFMA(wf, xf, acc[t]);
        }
      }
    }
    {
      const float* rrow = recv32 + (size_t)nc * 96;
      #pragma unroll
      for (int kb = 0; kb < 3; kb++) {
        f32x4 a0 = *(const f32x4*)(rrow + kb * 32 + lhi * 8);
        f32x4 a1 = *(const f32x4*)(rrow + kb * 32 + lhi * 8 + 4);
        u16x8 xf = {f2bf(a0[0]), f2bf(a0[1]), f2bf(a0[2]), f2bf(a0[3]),
                    f2bf(a1[0]), f2bf(a1[1]), f2bf(a1[2]), f2bf(a1[3])};
        #pragma unroll
        for (int t = 0; t < 6; t++) {
          u16x8 wf = *(const u16x8*)(wtc + (t * 16 + l15) * 96 + kb * 32 + lhi * 8);
          acc[t] = MFMA(wf, xf, acc[t]);
        }
      }
    }
    #pragma unroll
    for (int t = 0; t < 6; t++) {
      f32x4 cv = *(const f32x4*)(cvec + t * 16 + lhi * 4);
      u16x4 hp;
      #pragma unroll
      for (int j = 0; j < 4; j++) {
        float v = acc[t][j] + cv[j];
        v = v > 0.f ? v : 0.01f * v;
        hp[j] = f2bf(v);
      }
      *(u16x4*)&Hb[wave][l15][t * 16 + lhi * 4] = hp;
    }
    f32x4 o[6] = {};
    #pragma unroll
    for (int kb = 0; kb < 3; kb++) {
      u16x8 hf = *(const u16x8*)&Hb[wave][l15][kb * 32 + lhi * 8];
      #pragma unroll
      for (int t = 0; t < 6; t++) {
        u16x8 wf = *(const u16x8*)(wt2 + (t * 16 + l15) * 96 + kb * 32 + lhi * 8);
        o[t] = MFMA(wf, hf, o[t]);
      }
    }
    if (ncol < NN) {
      #pragma unroll
      for (int t = 0; t < 6; t++) {
        f32x4 bv = *(const f32x4*)(b2 + t * 16 + lhi * 4);
        f32x4 ov = o[t] + bv;
        u16x4 r = {f2bf(ov[0]), f2bf(ov[1]), f2bf(ov[2]), f2bf(ov[3])};
        *(u16x4*)(n_out + (size_t)ncol * 96 + t * 16 + lhi * 4) = r;
        if (out32) *(f32x4*)(out32 + (size_t)ncol * 96 + t * 16 + lhi * 4) = ov;
      }
    }
  }
}

// ---------------- global MLP (single WG) ----------------
__global__ void gn_global(const float* __restrict__ nsum, const float* __restrict__ esum,
                          float* gbuf, const float* __restrict__ gw1, const float* __restrict__ gb1,
                          const float* __restrict__ gw2, const float* __restrict__ gb2,
                          int s, float* outg) {
  __shared__ float x[288];
  __shared__ float h[96];
  int t = threadIdx.x;
  if (t < 96) { x[t] = nsum[t]; x[96 + t] = esum[t]; x[192 + t] = gbuf[t]; }
  __syncthreads();
  if (t < 96) {
    const float* W1 = gw1 + s * 288 * 96;
    float a = gb1[s * 96 + t];
    for (int k = 0; k < 288; k++) a += x[k] * W1[k * 96 + t];
    h[t] = a > 0.f ? a : 0.01f * a;
  }
  __syncthreads();
  if (t < 96) {
    const float* W2 = gw2 + s * 9216;
    float a = gb2[s * 96 + t];
    for (int k = 0; k < 96; k++) a += h[k] * W2[k * 96 + t];
    gbuf[t] = a;
    if (outg) outg[t] = a;
  }
}

// ---------------- host ----------------
extern "C" void kernel_launch(void* const* d_in, const int* in_sizes, int n_in,
                              void* d_out, int out_size, void* d_ws, size_t ws_size,
                              hipStream_t stream) {
  (void)in_sizes; (void)n_in; (void)out_size;
  const float* nodes    = (const float*)d_in[0];
  const float* edges    = (const float*)d_in[1];
  const float* globals_ = (const float*)d_in[2];
  const int*   senders  = (const int*)d_in[3];
  const int*   receivers= (const int*)d_in[4];
  const float* Wn = (const float*)d_in[5],  *bn = (const float*)d_in[6];
  const float* We = (const float*)d_in[7],  *be = (const float*)d_in[8];
  const float* Wg = (const float*)d_in[9],  *bg = (const float*)d_in[10];
  const float* ew1 = (const float*)d_in[11], *eb1 = (const float*)d_in[12];
  const float* ew2 = (const float*)d_in[13], *eb2 = (const float*)d_in[14];
  const float* nw1 = (const float*)d_in[15], *nb1 = (const float*)d_in[16];
  const float* nw2 = (const float*)d_in[17], *nb2 = (const float*)d_in[18];
  const float* gw1 = (const float*)d_in[19], *gb1 = (const float*)d_in[20];
  const float* gw2 = (const float*)d_in[21], *gb2 = (const float*)d_in[22];

  size_t off = 0;
  char* base = (char*)d_ws;
  auto A = [&](size_t bytes) -> void* {
    void* p = base + off;
    off = (off + bytes + 255) & ~(size_t)255;
    return p;
  };
  u16* e_bf    = (u16*)A((size_t)NE * FD * 2);     // sorted edge space
  u16* n_bf    = (u16*)A((size_t)NN * FD * 2);
  u16* ps      = (u16*)A((size_t)NN * FD * 2);
  u16* pr      = (u16*)A((size_t)NN * FD * 2);
  float* sent32= (float*)A((size_t)NN * FD * 4);
  float* recv32= (float*)A((size_t)NN * FD * 4);
  u16* wt_all  = (u16*)A((size_t)6 * 3 * 9216 * 2);
  u16* wf_all  = (u16*)A((size_t)2 * 3 * 9216 * 2);
  int* row_s   = (int*)A((size_t)(NN + 1) * 4);
  int* row_r   = (int*)A((size_t)(NN + 1) * 4);
  int* el_s    = (int*)A((size_t)NE * 4);
  int* el_r2   = (int*)A((size_t)NE * 4);
  int* pos_s   = (int*)A((size_t)NE * 4);
  int* snd_srt = (int*)A((size_t)NE * 4);
  int* rcv_srt = (int*)A((size_t)NE * 4);
  int* cur_s   = (int*)A((size_t)NN * 4);
  int* cur_r   = (int*)A((size_t)NN * 4);
  float* gbuf   = (float*)A(96 * 4);
  float* cvec_e = (float*)A(96 * 4);
  float* cvec_n = (float*)A(96 * 4);
  float* sums   = (float*)A(2 * 96 * 4);  // [0:96) nsum, [96:192) esum
  if (off > ws_size) return;  // insufficient scratch: bail

  float* out_n = (float*)d_out;
  float* out_e = out_n + (size_t)NN * FD;
  float* out_g = out_n + (size_t)NN * FD + (size_t)NE * FD;

  // WT blocks: 0 ew1_send, 1 ew1_recv, 2 nw1_n, 3 nw1_sent, 4 nw1_recv, 5 nw2
  auto WT = [&](int b, int s) { return wt_all + (size_t)(b * 3 + s) * 9216; };

  gn_wprep<<<648, 256, 0, stream>>>(ew1, nw1, nw2, wt_all);
  gn_wprep_frag<<<216, 256, 0, stream>>>(ew1, ew2, wf_all);
  gn_embed_n_mfma<<<(NN + 127) / 128, 256, 0, stream>>>(nodes, Wn, bn, n_bf);
  gn_gembed<<<1, 128, 0, stream>>>(globals_, Wg, bg, gbuf);

  hipMemsetAsync(cur_s, 0, (size_t)NN * 4, stream);
  hipMemsetAsync(cur_r, 0, (size_t)NN * 4, stream);
  gn_hist<<<(NE + 255) / 256, 256, 0, stream>>>(senders, receivers, cur_s, cur_r);
  gn_scan<<<1, 1024, 0, stream>>>(cur_s, row_s, cur_s, NN);
  gn_scan<<<1, 1024, 0, stream>>>(cur_r, row_r, cur_r, NN);
  gn_scatter2<<<(NE + 255) / 256, 256, 0, stream>>>(senders, receivers, cur_s, cur_r,
                                                    el_s, pos_s, el_r2, snd_srt, rcv_srt);
  gn_embed_e_mfma<<<NE / 128, 256, 0, stream>>>(edges, We, be, pos_s, e_bf);

  const int eblocks = NE / (16 * 4 * ETPW);   // 6250 blocks: 4 waves x 2 tiles

  for (int s = 0; s < 3; s++) {
    bool last = (s == 2);
    hipMemsetAsync(sums, 0, 2 * 96 * 4, stream);
    hipMemsetAsync(sent32, 0, (size_t)NN * FD * 4, stream);
    hipMemsetAsync(recv32, 0, (size_t)NN * FD * 4, stream);
    gn_cvec<<<2, 128, 0, stream>>>(gbuf, ew1, eb1, cvec_e, nw1, nb1, cvec_n, s);
    gn_proj<<<(NN + 127) / 128, 256, 0, stream>>>(n_bf, WT(0, s), WT(1, s), ps, pr);
    gn_edge4<<<eblocks, 256, 0, stream>>>(e_bf, ps, pr, snd_srt, rcv_srt, el_s,
                                          cvec_e, eb2 + s * 96,
                                          wf_all + (size_t)s * 9216,
                                          wf_all + (size_t)(3 + s) * 9216,
                                          sent32, recv32,
                                          last ? out_e : (float*)nullptr);
    gn_colsum32<<<256, 256, 0, stream>>>(sent32, sums + 96, NN);   // esum = sum of sent32
    gn_node<<<(NN + 127) / 128, 256, 0, stream>>>(n_bf, sent32, recv32,
                                                  WT(2, s), WT(3, s), WT(4, s), WT(5, s),
                                                  cvec_n, nb2 + s * 96, n_bf,
                                                  last ? out_n : (float*)nullptr);
    gn_colsum<<<256, 256, 0, stream>>>(n_bf, sums, NN);            // nsum
    gn_global<<<1, 128, 0, stream>>>(sums, sums + 96, gbuf, gw1, gb1, gw2, gb2, s,
                                     last ? out_g : (float*)nullptr);
  }
}

// Round 10
// 1676.102 us; speedup vs baseline: 1.9892x; 1.9892x over previous
//
#include <hip/hip_runtime.h>

typedef unsigned short u16;
typedef unsigned int u32;

#define NN 50000
#define NE 800000
#define FD 96

typedef float f32x4 __attribute__((ext_vector_type(4)));
typedef __bf16 bf16x8 __attribute__((ext_vector_type(8)));
typedef u16 u16x8 __attribute__((ext_vector_type(8)));
typedef u16 u16x4 __attribute__((ext_vector_type(4)));

__device__ __forceinline__ float bf2f(u16 u) { return __uint_as_float(((u32)u) << 16); }
__device__ __forceinline__ u16 f2bf(float f) {
  u32 u = __float_as_uint(f);
  u += 0x7fffu + ((u >> 16) & 1u);   // round-to-nearest-even
  return (u16)(u >> 16);
}

__device__ __forceinline__ f32x4 MFMA(u16x8 a, u16x8 b, f32x4 c) {
  return __builtin_amdgcn_mfma_f32_16x16x32_bf16(
      __builtin_bit_cast(bf16x8, a), __builtin_bit_cast(bf16x8, b), c, 0, 0, 0);
}

// ---------------- weight prep: fp32 -> bf16, transposed [n][k] blocks ----------------
// 6 blocks: 0 ew1[96:192] (proj send), 1 ew1[192:288] (proj recv),
//           2 nw1[0:96], 3 nw1[96:192], 4 nw1[192:288], 5 nw2
__global__ void gn_wprep(const float* __restrict__ ew1,
                         const float* __restrict__ nw1, const float* __restrict__ nw2,
                         u16* __restrict__ wt) {
  int gid = blockIdx.x * 256 + threadIdx.x;
  if (gid >= 6 * 3 * 9216) return;
  int b = gid / (3 * 9216);
  int rem = gid - b * 3 * 9216;
  int s = rem / 9216;
  int e = rem - s * 9216;
  int n = e / 96, k = e - n * 96;
  float v;
  switch (b) {
    case 0: v = ew1[s * 36864 + (96 + k) * 96 + n]; break;
    case 1: v = ew1[s * 36864 + (192 + k) * 96 + n]; break;
    case 2: v = nw1[s * 36864 + k * 96 + n]; break;
    case 3: v = nw1[s * 36864 + (96 + k) * 96 + n]; break;
    case 4: v = nw1[s * 36864 + (192 + k) * 96 + n]; break;
    default: v = nw2[s * 9216 + k * 96 + n]; break;
  }
  wt[gid] = f2bf(v);
}

// ---------------- fragment-major weight prep for edge kernel ----------------
__global__ void gn_wprep_frag(const float* __restrict__ ew1, const float* __restrict__ ew2,
                              u16* __restrict__ wf) {
  int gid = blockIdx.x * 256 + threadIdx.x;
  if (gid >= 2 * 3 * 9216) return;
  int b = gid / (3 * 9216);
  int rem = gid - b * 3 * 9216;
  int s = rem / 9216;
  int idx = rem - s * 9216;
  int j = idx & 7, lane = (idx >> 3) & 63, tkb = idx >> 9;
  int kb = tkb % 3, t = tkb / 3;
  int k = kb * 32 + (lane >> 4) * 8 + j;
  int n = t * 16 + (lane & 15);
  float v = (b == 0) ? ew1[s * 36864 + k * 96 + n] : ew2[s * 9216 + k * 96 + n];
  wf[gid] = f2bf(v);
}

// ---------------- embedders (MFMA, transposed-C) ----------------
__global__ __launch_bounds__(256) void gn_embed_e_mfma(
    const float* __restrict__ edges, const float* __restrict__ W,
    const float* __restrict__ b, const int* __restrict__ pos_s,
    u16* __restrict__ out) {
  __shared__ u16 WS[96][40];
  for (int i = threadIdx.x; i < 96 * 32; i += 256) {
    int n = i >> 5, k = i & 31;
    WS[n][k] = (k < 16) ? f2bf(W[k * 96 + n]) : (u16)0;
  }
  __syncthreads();
  const int wave = threadIdx.x >> 6, lane = threadIdx.x & 63;
  const int l15 = lane & 15, lhi = lane >> 4;
  #pragma unroll 1
  for (int grp = 0; grp < 2; grp++) {
    const long ec = (long)blockIdx.x * 128 + (wave * 2 + grp) * 16 + l15;
    const long dst = pos_s[ec];
    u16x8 xf = {0, 0, 0, 0, 0, 0, 0, 0};
    if (lhi < 2) {
      const float* er = edges + ec * 16 + lhi * 8;
      f32x4 e0 = *(const f32x4*)er;
      f32x4 e1 = *(const f32x4*)(er + 4);
      xf = (u16x8){f2bf(e0[0]), f2bf(e0[1]), f2bf(e0[2]), f2bf(e0[3]),
                   f2bf(e1[0]), f2bf(e1[1]), f2bf(e1[2]), f2bf(e1[3])};
    }
    #pragma unroll
    for (int t = 0; t < 6; t++) {
      u16x8 wf = *(const u16x8*)&WS[t * 16 + l15][lhi * 8];
      f32x4 acc = {};
      acc = MFMA(wf, xf, acc);
      f32x4 bv = *(const f32x4*)(b + t * 16 + lhi * 4);
      f32x4 ov = acc + bv;
      u16x4 r = {f2bf(ov[0]), f2bf(ov[1]), f2bf(ov[2]), f2bf(ov[3])};
      *(u16x4*)(out + dst * 96 + t * 16 + lhi * 4) = r;
    }
  }
}

__global__ __launch_bounds__(256) void gn_embed_n_mfma(
    const float* __restrict__ nodes, const float* __restrict__ W,
    const float* __restrict__ b, u16* __restrict__ out) {
  __shared__ u16 WS[96][40];
  for (int i = threadIdx.x; i < 96 * 32; i += 256) {
    int n = i >> 5, k = i & 31;
    WS[n][k] = f2bf(W[k * 96 + n]);
  }
  __syncthreads();
  const int wave = threadIdx.x >> 6, lane = threadIdx.x & 63;
  const int l15 = lane & 15, lhi = lane >> 4;
  #pragma unroll 1
  for (int grp = 0; grp < 2; grp++) {
    const int ncol = blockIdx.x * 128 + (wave * 2 + grp) * 16 + l15;
    const int nc = ncol < NN ? ncol : (NN - 1);
    const float* nr = nodes + (size_t)nc * 32 + lhi * 8;
    f32x4 e0 = *(const f32x4*)nr;
    f32x4 e1 = *(const f32x4*)(nr + 4);
    u16x8 xf = {f2bf(e0[0]), f2bf(e0[1]), f2bf(e0[2]), f2bf(e0[3]),
                f2bf(e1[0]), f2bf(e1[1]), f2bf(e1[2]), f2bf(e1[3])};
    if (ncol < NN) {
      #pragma unroll
      for (int t = 0; t < 6; t++) {
        u16x8 wf = *(const u16x8*)&WS[t * 16 + l15][lhi * 8];
        f32x4 acc = {};
        acc = MFMA(wf, xf, acc);
        f32x4 bv = *(const f32x4*)(b + t * 16 + lhi * 4);
        f32x4 ov = acc + bv;
        u16x4 r = {f2bf(ov[0]), f2bf(ov[1]), f2bf(ov[2]), f2bf(ov[3])};
        *(u16x4*)(out + (size_t)ncol * 96 + t * 16 + lhi * 4) = r;
      }
    }
  }
}

__global__ void gn_gembed(const float* __restrict__ g_in, const float* __restrict__ W,
                          const float* __restrict__ b, float* __restrict__ gbuf) {
  int f = threadIdx.x;
  if (f >= 96) return;
  float a = b[f];
  #pragma unroll
  for (int k = 0; k < 8; k++) a += g_in[k] * W[k * 96 + f];
  gbuf[f] = a;
}

// ---------------- CSR build ----------------
__global__ void gn_hist(const int* __restrict__ snd, const int* __restrict__ rcv,
                        int* __restrict__ cs, int* __restrict__ cr) {
  int i = blockIdx.x * 256 + threadIdx.x;
  if (i >= NE) return;
  atomicAdd(&cs[snd[i]], 1);
  atomicAdd(&cr[rcv[i]], 1);
}

__global__ void gn_scan(const int* cnt, int* row_ptr, int* cursor, int n) {
  __shared__ int lsum[1024];
  int t = threadIdx.x;
  int chunk = (n + 1023) >> 10;
  int s0 = t * chunk;
  int s1 = s0 + chunk; if (s1 > n) s1 = n;
  int s = 0;
  for (int i = s0; i < s1; i++) s += cnt[i];
  lsum[t] = s;
  __syncthreads();
  for (int off = 1; off < 1024; off <<= 1) {
    int v = (t >= off) ? lsum[t - off] : 0;
    __syncthreads();
    lsum[t] += v;
    __syncthreads();
  }
  if (t == 0) row_ptr[n] = lsum[1023];
  int prefix = (t == 0) ? 0 : lsum[t - 1];
  for (int i = s0; i < s1; i++) {
    int c = cnt[i];
    row_ptr[i] = prefix;
    cursor[i] = prefix;
    prefix += c;
  }
}

// scatter2: build sorted-space metadata.
__global__ void gn_scatter2(const int* __restrict__ snd, const int* __restrict__ rcv,
                            int* cur_s, int* cur_r,
                            int* __restrict__ el_s, int* __restrict__ pos_s,
                            int* __restrict__ el_r2,
                            int* __restrict__ snd_srt, int* __restrict__ rcv_srt) {
  int i = blockIdx.x * 256 + threadIdx.x;
  if (i >= NE) return;
  int s = snd[i], r = rcv[i];
  int p = atomicAdd(&cur_s[s], 1);
  int q = atomicAdd(&cur_r[r], 1);
  el_s[p] = i;
  pos_s[i] = p;
  el_r2[q] = p;
  snd_srt[p] = s;
  rcv_srt[p] = r;
}

// ---------------- segment sum, sender side: contiguous rows, 8x ILP ----------------
__global__ void gn_segsum_seq(const int* __restrict__ row_ptr,
                              const u16* __restrict__ e, u16* __restrict__ out) {
  int node = blockIdx.x * 4 + (threadIdx.x >> 6);
  int w = threadIdx.x & 63;
  if (w >= 48) return;
  int beg = row_ptr[node], end = row_ptr[node + 1];
  float ax[8] = {}, ay[8] = {};
  int j = beg;
  for (; j + 8 <= end; j += 8) {
    u32 v[8];
    #pragma unroll
    for (int q = 0; q < 8; q++) v[q] = ((const u32*)(e + (size_t)(j + q) * 96))[w];
    #pragma unroll
    for (int q = 0; q < 8; q++) {
      ax[q] += bf2f((u16)(v[q] & 0xffffu));
      ay[q] += bf2f((u16)(v[q] >> 16));
    }
  }
  for (; j < end; j++) {
    u32 v = ((const u32*)(e + (size_t)j * 96))[w];
    ax[0] += bf2f((u16)(v & 0xffffu)); ay[0] += bf2f((u16)(v >> 16));
  }
  float sx = ((ax[0] + ax[1]) + (ax[2] + ax[3])) + ((ax[4] + ax[5]) + (ax[6] + ax[7]));
  float sy = ((ay[0] + ay[1]) + (ay[2] + ay[3])) + ((ay[4] + ay[5]) + (ay[6] + ay[7]));
  ((u32*)(out + (size_t)node * 96))[w] = (u32)f2bf(sx) | ((u32)f2bf(sy) << 16);
}

// ---------------- segment sum, receiver side: gather sorted positions, 8x ILP ----------------
__global__ void gn_segsum(const int* __restrict__ row_ptr, const int* __restrict__ el,
                          const u16* __restrict__ e, u16* __restrict__ out) {
  int node = blockIdx.x * 4 + (threadIdx.x >> 6);
  int w = threadIdx.x & 63;
  if (w >= 48) return;
  int beg = row_ptr[node], end = row_ptr[node + 1];
  float ax[8] = {}, ay[8] = {};
  int j = beg;
  for (; j + 8 <= end; j += 8) {
    u32 v[8];
    #pragma unroll
    for (int q = 0; q < 8; q++) v[q] = ((const u32*)(e + (size_t)el[j + q] * 96))[w];
    #pragma unroll
    for (int q = 0; q < 8; q++) {
      ax[q] += bf2f((u16)(v[q] & 0xffffu));
      ay[q] += bf2f((u16)(v[q] >> 16));
    }
  }
  for (; j < end; j++) {
    u32 v = ((const u32*)(e + (size_t)el[j] * 96))[w];
    ax[0] += bf2f((u16)(v & 0xffffu)); ay[0] += bf2f((u16)(v >> 16));
  }
  float sx = ((ax[0] + ax[1]) + (ax[2] + ax[3])) + ((ax[4] + ax[5]) + (ax[6] + ax[7]));
  float sy = ((ay[0] + ay[1]) + (ay[2] + ay[3])) + ((ay[4] + ay[5]) + (ay[6] + ay[7]));
  ((u32*)(out + (size_t)node * 96))[w] = (u32)f2bf(sx) | ((u32)f2bf(sy) << 16);
}

// ---------------- column sum of bf16 [M][96] -> atomicAdd float[96] ----------------
__global__ void gn_colsum(const u16* __restrict__ x, float* __restrict__ out, int M) {
  int w = threadIdx.x & 63;
  int rg = threadIdx.x >> 6;
  if (w >= 48) return;
  float ax = 0.f, ay = 0.f;
  for (int r = blockIdx.x * 4 + rg; r < M; r += gridDim.x * 4) {
    u32 v = ((const u32*)(x + (size_t)r * 96))[w];
    ax += bf2f((u16)(v & 0xffffu));
    ay += bf2f((u16)(v >> 16));
  }
  atomicAdd(&out[2 * w], ax);
  atomicAdd(&out[2 * w + 1], ay);
}

// ---------------- per-step constant vectors: cvec = g @ W_gblock + b1 ----------------
__global__ void gn_cvec(const float* __restrict__ g, const float* __restrict__ ew1,
                        const float* __restrict__ eb1, float* __restrict__ cve,
                        const float* __restrict__ nw1, const float* __restrict__ nb1,
                        float* __restrict__ cvn, int s) {
  int f = threadIdx.x;
  if (f >= 96) return;
  const float* W = (blockIdx.x == 0 ? ew1 : nw1) + s * 36864 + 288 * 96;
  const float* b = (blockIdx.x == 0 ? eb1 : nb1) + s * 96;
  float* o = blockIdx.x == 0 ? cve : cvn;
  float a = b[f];
  for (int k = 0; k < 96; k++) a += g[k] * W[k * 96 + f];
  o[f] = a;
}

// ---------------- node projections: ps = n@ew1[96:192], pr = n@ew1[192:288] ----------------
__global__ __launch_bounds__(256) void gn_proj(const u16* __restrict__ n_in,
                                               const u16* __restrict__ wts, const u16* __restrict__ wtr,
                                               u16* __restrict__ ps, u16* __restrict__ pr) {
  __shared__ u16 WS[96][104];
  __shared__ u16 WR[96][104];
  for (int i = threadIdx.x; i < 96 * 48; i += 256) {
    int n = i / 48, k2 = (i - n * 48) * 2;
    *(u32*)&WS[n][k2] = ((const u32*)wts)[i];
    *(u32*)&WR[n][k2] = ((const u32*)wtr)[i];
  }
  __syncthreads();
  const int wave = threadIdx.x >> 6, lane = threadIdx.x & 63;
  const int l15 = lane & 15, lhi = lane >> 4;
  #pragma unroll 1
  for (int grp = 0; grp < 2; grp++) {
    const int gidx = wave * 2 + grp;
    const int ncol = blockIdx.x * 128 + gidx * 16 + l15;
    const int nc = ncol < NN ? ncol : (NN - 1);
    const u16* row = n_in + (size_t)nc * 96;
    u16x8 xf0 = *(const u16x8*)(row + 0 * 32 + lhi * 8);
    u16x8 xf1 = *(const u16x8*)(row + 1 * 32 + lhi * 8);
    u16x8 xf2 = *(const u16x8*)(row + 2 * 32 + lhi * 8);
    f32x4 a[6] = {}, b[6] = {};
    #pragma unroll
    for (int kb = 0; kb < 3; kb++) {
      u16x8 xf = (kb == 0) ? xf0 : ((kb == 1) ? xf1 : xf2);
      #pragma unroll
      for (int t = 0; t < 6; t++) {
        u16x8 wfa = *(const u16x8*)&WS[t * 16 + l15][kb * 32 + lhi * 8];
        u16x8 wfb = *(const u16x8*)&WR[t * 16 + l15][kb * 32 + lhi * 8];
        a[t] = MFMA(wfa, xf, a[t]);
        b[t] = MFMA(wfb, xf, b[t]);
      }
    }
    if (ncol < NN) {
      #pragma unroll
      for (int t = 0; t < 6; t++) {
        u16x4 ra = {f2bf(a[t][0]), f2bf(a[t][1]), f2bf(a[t][2]), f2bf(a[t][3])};
        u16x4 rb = {f2bf(b[t][0]), f2bf(b[t][1]), f2bf(b[t][2]), f2bf(b[t][3])};
        *(u16x4*)(ps + (size_t)ncol * 96 + t * 16 + lhi * 4) = ra;
        *(u16x4*)(pr + (size_t)ncol * 96 + t * 16 + lhi * 4) = rb;
      }
    }
  }
}

// ---------------- edge MLP v5: staged coalesced epilogue, NO atomics ----------------
#define ETPW 5
#define SB_P 104   // staged row pitch in u16 (208 B, 16-B aligned)
__global__ __launch_bounds__(512) void gn_edge5(
    u16* __restrict__ e_st,
    const u16* __restrict__ ps, const u16* __restrict__ pr,
    const int* __restrict__ snd, const int* __restrict__ rcv,   // sorted-space
    const int* __restrict__ el_s,                               // sorted pos -> orig edge
    const float* __restrict__ cvec, const float* __restrict__ b2,
    const u16* __restrict__ wf1, const u16* __restrict__ wf2,
    float* __restrict__ out32) {
  __shared__ u16 W1[1152 * 8];     // fragment-major
  __shared__ u16 W2[1152 * 8];
  __shared__ u16 Hb[8][16 * SB_P]; // per-wave scratch: H-frag region + staged tile (time-shared)
  for (int i = threadIdx.x; i < 1152; i += 512) {
    *(u16x8*)&W1[i * 8] = *(const u16x8*)(wf1 + (size_t)i * 8);
    *(u16x8*)&W2[i * 8] = *(const u16x8*)(wf2 + (size_t)i * 8);
  }
  __syncthreads();
  const int wave = threadIdx.x >> 6, lane = threadIdx.x & 63;
  const int l15 = lane & 15, lhi = lane >> 4;
  u16* myH = Hb[wave];
  const long t0 = ((long)blockIdx.x * 8 + wave) * ETPW;

  int r3[3], o3[3];
  #pragma unroll
  for (int s3 = 0; s3 < 3; s3++) { int g = s3 * 512 + lane * 8; r3[s3] = g / 96; o3[s3] = g - 96 * r3[s3]; }
  int r6[6], o6[6];
  #pragma unroll
  for (int s6 = 0; s6 < 6; s6++) { int g = s6 * 256 + lane * 4; r6[s6] = g / 96; o6[s6] = g - 96 * r6[s6]; }

  u16x8 xf0, xf1, xf2;
  u16x4 ga[6], gb[6];
  u16x8 nxf0, nxf1, nxf2; int nsi = 0, nri = 0;
  u16x4 nga[6], ngb[6];

  {
    const u16* erow = e_st + (t0 * 16 + l15) * 96;
    xf0 = *(const u16x8*)(erow + lhi * 8);
    xf1 = *(const u16x8*)(erow + 32 + lhi * 8);
    xf2 = *(const u16x8*)(erow + 64 + lhi * 8);
    int si = snd[t0 * 16 + l15], ri = rcv[t0 * 16 + l15];
    const u16* pa = ps + (size_t)si * 96 + lhi * 4;
    const u16* pb = pr + (size_t)ri * 96 + lhi * 4;
    #pragma unroll
    for (int t = 0; t < 6; t++) { ga[t] = *(const u16x4*)(pa + t * 16); gb[t] = *(const u16x4*)(pb + t * 16); }
  }

  #pragma unroll 1
  for (int it = 0; it < ETPW; it++) {
    const long tb = (t0 + it) * 16;            // first edge pos of tile
    const long ecol = tb + l15;
    if (it + 1 < ETPW) {
      const u16* erow = e_st + (ecol + 16) * 96;
      nxf0 = *(const u16x8*)(erow + lhi * 8);
      nxf1 = *(const u16x8*)(erow + 32 + lhi * 8);
      nxf2 = *(const u16x8*)(erow + 64 + lhi * 8);
      nsi = snd[ecol + 16]; nri = rcv[ecol + 16];
    }
    // GEMM1
    f32x4 acc[6] = {};
    #pragma unroll
    for (int t = 0; t < 6; t++) acc[t] = MFMA(*(const u16x8*)&W1[((t * 3 + 0) * 64 + lane) * 8], xf0, acc[t]);
    #pragma unroll
    for (int t = 0; t < 6; t++) acc[t] = MFMA(*(const u16x8*)&W1[((t * 3 + 1) * 64 + lane) * 8], xf1, acc[t]);
    #pragma unroll
    for (int t = 0; t < 6; t++) acc[t] = MFMA(*(const u16x8*)&W1[((t * 3 + 2) * 64 + lane) * 8], xf2, acc[t]);
    if (it + 1 < ETPW) {
      const u16* pa = ps + (size_t)nsi * 96 + lhi * 4;
      const u16* pb = pr + (size_t)nri * 96 + lhi * 4;
      #pragma unroll
      for (int t = 0; t < 6; t++) { nga[t] = *(const u16x4*)(pa + t * 16); ngb[t] = *(const u16x4*)(pb + t * 16); }
    }
    // guard: previous iteration's staged reads done before H-frag rewrite
    asm volatile("s_waitcnt lgkmcnt(0)" ::: "memory");
    __builtin_amdgcn_sched_barrier(0);
    // epilogue 1: add gathers + cvec, leaky-relu, write H fragment-major
    #pragma unroll
    for (int t = 0; t < 6; t++) {
      f32x4 cv = *(const f32x4*)(cvec + t * 16 + lhi * 4);
      u16x4 hp;
      #pragma unroll
      for (int j = 0; j < 4; j++) {
        float v = acc[t][j] + bf2f(ga[t][j]) + bf2f(gb[t][j]) + cv[j];
        v = v > 0.f ? v : 0.01f * v;
        hp[j] = f2bf(v);
      }
      int q = (4 * t + lhi) & 7;
      int kb2 = (4 * t + lhi) >> 3;
      *(u16x4*)&myH[(kb2 * 64 + (q >> 1) * 16 + l15) * 8 + (q & 1) * 4] = hp;
    }
    // GEMM2
    f32x4 o[6] = {};
    #pragma unroll
    for (int kb = 0; kb < 3; kb++) {
      u16x8 hf = *(const u16x8*)&myH[(kb * 64 + lane) * 8];
      #pragma unroll
      for (int t = 0; t < 6; t++)
        o[t] = MFMA(*(const u16x8*)&W2[((t * 3 + kb) * 64 + lane) * 8], hf, o[t]);
    }
    // stage bf16 tile [16][SB_P]
    asm volatile("s_waitcnt lgkmcnt(0)" ::: "memory");
    __builtin_amdgcn_sched_barrier(0);
    #pragma unroll
    for (int t = 0; t < 6; t++) {
      f32x4 bv = *(const f32x4*)(b2 + t * 16 + lhi * 4);
      f32x4 ov = o[t] + bv;
      u16x4 r4 = {f2bf(ov[0]), f2bf(ov[1]), f2bf(ov[2]), f2bf(ov[3])};
      *(u16x4*)&myH[l15 * SB_P + t * 16 + lhi * 4] = r4;
    }
    asm volatile("s_waitcnt lgkmcnt(0)" ::: "memory");
    __builtin_amdgcn_sched_barrier(0);
    // coalesced e_st store: 3 x 1KB contiguous bursts
    #pragma unroll
    for (int s3 = 0; s3 < 3; s3++) {
      u16x8 v = *(const u16x8*)&myH[r3[s3] * SB_P + o3[s3]];
      *(u16x8*)(e_st + tb * 96 + s3 * 512 + lane * 8) = v;
    }
    // out32 (last step): scatter rows to original edge order
    if (out32) {
      #pragma unroll
      for (int s6 = 0; s6 < 6; s6++) {
        long oc = el_s[tb + r6[s6]];
        u16x4 v = *(const u16x4*)&myH[r6[s6] * SB_P + o6[s6]];
        f32x4 f = {bf2f(v[0]), bf2f(v[1]), bf2f(v[2]), bf2f(v[3])};
        *(f32x4*)(out32 + oc * 96 + o6[s6]) = f;
      }
    }
    xf0 = nxf0; xf1 = nxf1; xf2 = nxf2;
    #pragma unroll
    for (int t = 0; t < 6; t++) { ga[t] = nga[t]; gb[t] = ngb[t]; }
  }
}

// ---------------- node MLP (K=288 over n/sent/recv bf16 blocks) ----------------
__global__ __launch_bounds__(256) void gn_node(
    const u16* __restrict__ n_in, const u16* __restrict__ sent, const u16* __restrict__ recv,
    const u16* __restrict__ wta, const u16* __restrict__ wtb, const u16* __restrict__ wtc,
    const u16* __restrict__ wt2,
    const float* __restrict__ cvec, const float* __restrict__ b2,
    u16* __restrict__ n_out, float* __restrict__ out32) {
  __shared__ u16 WA[96][104];
  __shared__ u16 WB[96][104];
  __shared__ u16 Hb[4][16][104];
  for (int i = threadIdx.x; i < 96 * 48; i += 256) {
    int n = i / 48, k2 = (i - n * 48) * 2;
    *(u32*)&WA[n][k2] = ((const u32*)wta)[i];
    *(u32*)&WB[n][k2] = ((const u32*)wtb)[i];
  }
  __syncthreads();
  const int wave = threadIdx.x >> 6, lane = threadIdx.x & 63;
  const int l15 = lane & 15, lhi = lane >> 4;
  #pragma unroll 1
  for (int grp = 0; grp < 2; grp++) {
    const int gidx = wave * 2 + grp;
    const int ncol = blockIdx.x * 128 + gidx * 16 + l15;
    const int nc = ncol < NN ? ncol : (NN - 1);
    f32x4 acc[6] = {};
    {
      const u16* row = n_in + (size_t)nc * 96;
      #pragma unroll
      for (int kb = 0; kb < 3; kb++) {
        u16x8 xf = *(const u16x8*)(row + kb * 32 + lhi * 8);
        #pragma unroll
        for (int t = 0; t < 6; t++) {
          u16x8 wf = *(const u16x8*)&WA[t * 16 + l15][kb * 32 + lhi * 8];
          acc[t] = MFMA(wf, xf, acc[t]);
        }
      }
    }
    {
      const u16* row = sent + (size_t)nc * 96;
      #pragma unroll
      for (int kb = 0; kb < 3; kb++) {
        u16x8 xf = *(const u16x8*)(row + kb * 32 + lhi * 8);
        #pragma unroll
        for (int t = 0; t < 6; t++) {
          u16x8 wf = *(const u16x8*)&WB[t * 16 + l15][kb * 32 + lhi * 8];
          acc[t] = MFMA(wf, xf, acc[t]);
        }
      }
    }
    {
      const u16* row = recv + (size_t)nc * 96;
      #pragma unroll
      for (int kb = 0; kb < 3; kb++) {
        u16x8 xf = *(const u16x8*)(row + kb * 32 + lhi * 8);
        #pragma unroll
        for (int t = 0; t < 6; t++) {
          u16x8 wf = *(const u16x8*)(wtc + (t * 16 + l15) * 96 + kb * 32 + lhi * 8);
          acc[t] = MFMA(wf, xf, acc[t]);
        }
      }
    }
    #pragma unroll
    for (int t = 0; t < 6; t++) {
      f32x4 cv = *(const f32x4*)(cvec + t * 16 + lhi * 4);
      u16x4 hp;
      #pragma unroll
      for (int j = 0; j < 4; j++) {
        float v = acc[t][j] + cv[j];
        v = v > 0.f ? v : 0.01f * v;
        hp[j] = f2bf(v);
      }
      *(u16x4*)&Hb[wave][l15][t * 16 + lhi * 4] = hp;
    }
    f32x4 o[6] = {};
    #pragma unroll
    for (int kb = 0; kb < 3; kb++) {
      u16x8 hf = *(const u16x8*)&Hb[wave][l15][kb * 32 + lhi * 8];
      #pragma unroll
      for (int t = 0; t < 6; t++) {
        u16x8 wf = *(const u16x8*)(wt2 + (t * 16 + l15) * 96 + kb * 32 + lhi * 8);
        o[t] = MFMA(wf, hf, o[t]);
      }
    }
    if (ncol < NN) {
      #pragma unroll
      for (int t = 0; t < 6; t++) {
        f32x4 bv = *(const f32x4*)(b2 + t * 16 + lhi * 4);
        f32x4 ov = o[t] + bv;
        u16x4 r = {f2bf(ov[0]), f2bf(ov[1]), f2bf(ov[2]), f2bf(ov[3])};
        *(u16x4*)(n_out + (size_t)ncol * 96 + t * 16 + lhi * 4) = r;
        if (out32) *(f32x4*)(out32 + (size_t)ncol * 96 + t * 16 + lhi * 4) = ov;
      }
    }
  }
}

// ---------------- global MLP (single WG) ----------------
__global__ void gn_global(const float* __restrict__ nsum, const float* __restrict__ esum,
                          float* gbuf, const float* __restrict__ gw1, const float* __restrict__ gb1,
                          const float* __restrict__ gw2, const float* __restrict__ gb2,
                          int s, float* outg) {
  __shared__ float x[288];
  __shared__ float h[96];
  int t = threadIdx.x;
  if (t < 96) { x[t] = nsum[t]; x[96 + t] = esum[t]; x[192 + t] = gbuf[t]; }
  __syncthreads();
  if (t < 96) {
    const float* W1 = gw1 + s * 288 * 96;
    float a = gb1[s * 96 + t];
    for (int k = 0; k < 288; k++) a += x[k] * W1[k * 96 + t];
    h[t] = a > 0.f ? a : 0.01f * a;
  }
  __syncthreads();
  if (t < 96) {
    const float* W2 = gw2 + s * 9216;
    float a = gb2[s * 96 + t];
    for (int k = 0; k < 96; k++) a += h[k] * W2[k * 96 + t];
    gbuf[t] = a;
    if (outg) outg[t] = a;
  }
}

// ---------------- host ----------------
extern "C" void kernel_launch(void* const* d_in, const int* in_sizes, int n_in,
                              void* d_out, int out_size, void* d_ws, size_t ws_size,
                              hipStream_t stream) {
  (void)in_sizes; (void)n_in; (void)out_size;
  const float* nodes    = (const float*)d_in[0];
  const float* edges    = (const float*)d_in[1];
  const float* globals_ = (const float*)d_in[2];
  const int*   senders  = (const int*)d_in[3];
  const int*   receivers= (const int*)d_in[4];
  const float* Wn = (const float*)d_in[5],  *bn = (const float*)d_in[6];
  const float* We = (const float*)d_in[7],  *be = (const float*)d_in[8];
  const float* Wg = (const float*)d_in[9],  *bg = (const float*)d_in[10];
  const float* ew1 = (const float*)d_in[11], *eb1 = (const float*)d_in[12];
  const float* ew2 = (const float*)d_in[13], *eb2 = (const float*)d_in[14];
  const float* nw1 = (const float*)d_in[15], *nb1 = (const float*)d_in[16];
  const float* nw2 = (const float*)d_in[17], *nb2 = (const float*)d_in[18];
  const float* gw1 = (const float*)d_in[19], *gb1 = (const float*)d_in[20];
  const float* gw2 = (const float*)d_in[21], *gb2 = (const float*)d_in[22];

  size_t off = 0;
  char* base = (char*)d_ws;
  auto A = [&](size_t bytes) -> void* {
    void* p = base + off;
    off = (off + bytes + 255) & ~(size_t)255;
    return p;
  };
  u16* e_bf    = (u16*)A((size_t)NE * FD * 2);     // sorted edge space
  u16* n_bf    = (u16*)A((size_t)NN * FD * 2);
  u16* ps      = (u16*)A((size_t)NN * FD * 2);
  u16* pr      = (u16*)A((size_t)NN * FD * 2);
  u16* sent    = (u16*)A((size_t)NN * FD * 2);
  u16* recv    = (u16*)A((size_t)NN * FD * 2);
  u16* wt_all  = (u16*)A((size_t)6 * 3 * 9216 * 2);
  u16* wf_all  = (u16*)A((size_t)2 * 3 * 9216 * 2);
  int* row_s   = (int*)A((size_t)(NN + 1) * 4);
  int* row_r   = (int*)A((size_t)(NN + 1) * 4);
  int* el_s    = (int*)A((size_t)NE * 4);
  int* el_r2   = (int*)A((size_t)NE * 4);
  int* pos_s   = (int*)A((size_t)NE * 4);
  int* snd_srt = (int*)A((size_t)NE * 4);
  int* rcv_srt = (int*)A((size_t)NE * 4);
  int* cur_s   = (int*)A((size_t)NN * 4);
  int* cur_r   = (int*)A((size_t)NN * 4);
  float* gbuf   = (float*)A(96 * 4);
  float* cvec_e = (float*)A(96 * 4);
  float* cvec_n = (float*)A(96 * 4);
  float* sums   = (float*)A(2 * 96 * 4);  // [0:96) nsum, [96:192) esum
  if (off > ws_size) return;  // insufficient scratch: bail

  float* out_n = (float*)d_out;
  float* out_e = out_n + (size_t)NN * FD;
  float* out_g = out_n + (size_t)NN * FD + (size_t)NE * FD;

  // WT blocks: 0 ew1_send, 1 ew1_recv, 2 nw1_n, 3 nw1_sent, 4 nw1_recv, 5 nw2
  auto WT = [&](int b, int s) { return wt_all + (size_t)(b * 3 + s) * 9216; };

  gn_wprep<<<648, 256, 0, stream>>>(ew1, nw1, nw2, wt_all);
  gn_wprep_frag<<<216, 256, 0, stream>>>(ew1, ew2, wf_all);
  gn_embed_n_mfma<<<(NN + 127) / 128, 256, 0, stream>>>(nodes, Wn, bn, n_bf);
  gn_gembed<<<1, 128, 0, stream>>>(globals_, Wg, bg, gbuf);

  hipMemsetAsync(cur_s, 0, (size_t)NN * 4, stream);
  hipMemsetAsync(cur_r, 0, (size_t)NN * 4, stream);
  gn_hist<<<(NE + 255) / 256, 256, 0, stream>>>(senders, receivers, cur_s, cur_r);
  gn_scan<<<1, 1024, 0, stream>>>(cur_s, row_s, cur_s, NN);
  gn_scan<<<1, 1024, 0, stream>>>(cur_r, row_r, cur_r, NN);
  gn_scatter2<<<(NE + 255) / 256, 256, 0, stream>>>(senders, receivers, cur_s, cur_r,
                                                    el_s, pos_s, el_r2, snd_srt, rcv_srt);
  gn_embed_e_mfma<<<NE / 128, 256, 0, stream>>>(edges, We, be, pos_s, e_bf);

  const int eblocks = NE / (16 * 8 * ETPW);   // 1250 blocks: 8 waves x 5 tiles

  for (int s = 0; s < 3; s++) {
    bool last = (s == 2);
    hipMemsetAsync(sums, 0, 2 * 96 * 4, stream);
    gn_cvec<<<2, 128, 0, stream>>>(gbuf, ew1, eb1, cvec_e, nw1, nb1, cvec_n, s);
    gn_proj<<<(NN + 127) / 128, 256, 0, stream>>>(n_bf, WT(0, s), WT(1, s), ps, pr);
    gn_edge5<<<eblocks, 512, 0, stream>>>(e_bf, ps, pr, snd_srt, rcv_srt, el_s,
                                          cvec_e, eb2 + s * 96,
                                          wf_all + (size_t)s * 9216,
                                          wf_all + (size_t)(3 + s) * 9216,
                                          last ? out_e : (float*)nullptr);
    gn_segsum_seq<<<NN / 4, 256, 0, stream>>>(row_s, e_bf, sent);
    gn_segsum<<<NN / 4, 256, 0, stream>>>(row_r, el_r2, e_bf, recv);
    gn_colsum<<<256, 256, 0, stream>>>(sent, sums + 96, NN);       // esum
    gn_node<<<(NN + 127) / 128, 256, 0, stream>>>(n_bf, sent, recv,
                                                  WT(2, s), WT(3, s), WT(4, s), WT(5, s),
                                                  cvec_n, nb2 + s * 96, n_bf,
                                                  last ? out_n : (float*)nullptr);
    gn_colsum<<<256, 256, 0, stream>>>(n_bf, sums, NN);            // nsum
    gn_global<<<1, 128, 0, stream>>>(sums, sums + 96, gbuf, gw1, gb1, gw2, gb2, s,
                                     last ? out_g : (float*)nullptr);
  }
}

// Round 11
// 1562.394 us; speedup vs baseline: 2.1340x; 1.0728x over previous
//
#include <hip/hip_runtime.h>

typedef unsigned short u16;
typedef unsigned int u32;

#define NN 50000
#define NE 800000
#define FD 96

typedef float f32x4 __attribute__((ext_vector_type(4)));
typedef __bf16 bf16x8 __attribute__((ext_vector_type(8)));
typedef u16 u16x8 __attribute__((ext_vector_type(8)));
typedef u16 u16x4 __attribute__((ext_vector_type(4)));

__device__ __forceinline__ float bf2f(u16 u) { return __uint_as_float(((u32)u) << 16); }
__device__ __forceinline__ u16 f2bf(float f) {
  return __builtin_bit_cast(u16, (__bf16)f);   // native RNE; compiler pairs into v_cvt_pk_bf16_f32
}

__device__ __forceinline__ f32x4 MFMA(u16x8 a, u16x8 b, f32x4 c) {
  return __builtin_amdgcn_mfma_f32_16x16x32_bf16(
      __builtin_bit_cast(bf16x8, a), __builtin_bit_cast(bf16x8, b), c, 0, 0, 0);
}

// ---------------- weight prep: fp32 -> bf16, transposed [n][k] blocks ----------------
// 6 blocks: 0 ew1[96:192] (proj send), 1 ew1[192:288] (proj recv),
//           2 nw1[0:96], 3 nw1[96:192], 4 nw1[192:288], 5 nw2
__global__ void gn_wprep(const float* __restrict__ ew1,
                         const float* __restrict__ nw1, const float* __restrict__ nw2,
                         u16* __restrict__ wt) {
  int gid = blockIdx.x * 256 + threadIdx.x;
  if (gid >= 6 * 3 * 9216) return;
  int b = gid / (3 * 9216);
  int rem = gid - b * 3 * 9216;
  int s = rem / 9216;
  int e = rem - s * 9216;
  int n = e / 96, k = e - n * 96;
  float v;
  switch (b) {
    case 0: v = ew1[s * 36864 + (96 + k) * 96 + n]; break;
    case 1: v = ew1[s * 36864 + (192 + k) * 96 + n]; break;
    case 2: v = nw1[s * 36864 + k * 96 + n]; break;
    case 3: v = nw1[s * 36864 + (96 + k) * 96 + n]; break;
    case 4: v = nw1[s * 36864 + (192 + k) * 96 + n]; break;
    default: v = nw2[s * 9216 + k * 96 + n]; break;
  }
  wt[gid] = f2bf(v);
}

// ---------------- fragment-major weight prep for edge kernel ----------------
__global__ void gn_wprep_frag(const float* __restrict__ ew1, const float* __restrict__ ew2,
                              u16* __restrict__ wf) {
  int gid = blockIdx.x * 256 + threadIdx.x;
  if (gid >= 2 * 3 * 9216) return;
  int b = gid / (3 * 9216);
  int rem = gid - b * 3 * 9216;
  int s = rem / 9216;
  int idx = rem - s * 9216;
  int j = idx & 7, lane = (idx >> 3) & 63, tkb = idx >> 9;
  int kb = tkb % 3, t = tkb / 3;
  int k = kb * 32 + (lane >> 4) * 8 + j;
  int n = t * 16 + (lane & 15);
  float v = (b == 0) ? ew1[s * 36864 + k * 96 + n] : ew2[s * 9216 + k * 96 + n];
  wf[gid] = f2bf(v);
}

// ---------------- embedders (MFMA, transposed-C) ----------------
__global__ __launch_bounds__(256) void gn_embed_e_mfma(
    const float* __restrict__ edges, const float* __restrict__ W,
    const float* __restrict__ b, const int* __restrict__ pos_s,
    u16* __restrict__ out) {
  __shared__ u16 WS[96][40];
  for (int i = threadIdx.x; i < 96 * 32; i += 256) {
    int n = i >> 5, k = i & 31;
    WS[n][k] = (k < 16) ? f2bf(W[k * 96 + n]) : (u16)0;
  }
  __syncthreads();
  const int wave = threadIdx.x >> 6, lane = threadIdx.x & 63;
  const int l15 = lane & 15, lhi = lane >> 4;
  #pragma unroll 1
  for (int grp = 0; grp < 2; grp++) {
    const long ec = (long)blockIdx.x * 128 + (wave * 2 + grp) * 16 + l15;
    const long dst = pos_s[ec];
    u16x8 xf = {0, 0, 0, 0, 0, 0, 0, 0};
    if (lhi < 2) {
      const float* er = edges + ec * 16 + lhi * 8;
      f32x4 e0 = *(const f32x4*)er;
      f32x4 e1 = *(const f32x4*)(er + 4);
      xf = (u16x8){f2bf(e0[0]), f2bf(e0[1]), f2bf(e0[2]), f2bf(e0[3]),
                   f2bf(e1[0]), f2bf(e1[1]), f2bf(e1[2]), f2bf(e1[3])};
    }
    #pragma unroll
    for (int t = 0; t < 6; t++) {
      u16x8 wf = *(const u16x8*)&WS[t * 16 + l15][lhi * 8];
      f32x4 acc = {};
      acc = MFMA(wf, xf, acc);
      f32x4 bv = *(const f32x4*)(b + t * 16 + lhi * 4);
      f32x4 ov = acc + bv;
      u16x4 r = {f2bf(ov[0]), f2bf(ov[1]), f2bf(ov[2]), f2bf(ov[3])};
      *(u16x4*)(out + dst * 96 + t * 16 + lhi * 4) = r;
    }
  }
}

__global__ __launch_bounds__(256) void gn_embed_n_mfma(
    const float* __restrict__ nodes, const float* __restrict__ W,
    const float* __restrict__ b, u16* __restrict__ out) {
  __shared__ u16 WS[96][40];
  for (int i = threadIdx.x; i < 96 * 32; i += 256) {
    int n = i >> 5, k = i & 31;
    WS[n][k] = f2bf(W[k * 96 + n]);
  }
  __syncthreads();
  const int wave = threadIdx.x >> 6, lane = threadIdx.x & 63;
  const int l15 = lane & 15, lhi = lane >> 4;
  #pragma unroll 1
  for (int grp = 0; grp < 2; grp++) {
    const int ncol = blockIdx.x * 128 + (wave * 2 + grp) * 16 + l15;
    const int nc = ncol < NN ? ncol : (NN - 1);
    const float* nr = nodes + (size_t)nc * 32 + lhi * 8;
    f32x4 e0 = *(const f32x4*)nr;
    f32x4 e1 = *(const f32x4*)(nr + 4);
    u16x8 xf = {f2bf(e0[0]), f2bf(e0[1]), f2bf(e0[2]), f2bf(e0[3]),
                f2bf(e1[0]), f2bf(e1[1]), f2bf(e1[2]), f2bf(e1[3])};
    if (ncol < NN) {
      #pragma unroll
      for (int t = 0; t < 6; t++) {
        u16x8 wf = *(const u16x8*)&WS[t * 16 + l15][lhi * 8];
        f32x4 acc = {};
        acc = MFMA(wf, xf, acc);
        f32x4 bv = *(const f32x4*)(b + t * 16 + lhi * 4);
        f32x4 ov = acc + bv;
        u16x4 r = {f2bf(ov[0]), f2bf(ov[1]), f2bf(ov[2]), f2bf(ov[3])};
        *(u16x4*)(out + (size_t)ncol * 96 + t * 16 + lhi * 4) = r;
      }
    }
  }
}

__global__ void gn_gembed(const float* __restrict__ g_in, const float* __restrict__ W,
                          const float* __restrict__ b, float* __restrict__ gbuf) {
  int f = threadIdx.x;
  if (f >= 96) return;
  float a = b[f];
  #pragma unroll
  for (int k = 0; k < 8; k++) a += g_in[k] * W[k * 96 + f];
  gbuf[f] = a;
}

// ---------------- CSR build ----------------
__global__ void gn_hist(const int* __restrict__ snd, const int* __restrict__ rcv,
                        int* __restrict__ cs, int* __restrict__ cr) {
  int i = blockIdx.x * 256 + threadIdx.x;
  if (i >= NE) return;
  atomicAdd(&cs[snd[i]], 1);
  atomicAdd(&cr[rcv[i]], 1);
}

__global__ void gn_scan(const int* cnt, int* row_ptr, int* cursor, int n) {
  __shared__ int lsum[1024];
  int t = threadIdx.x;
  int chunk = (n + 1023) >> 10;
  int s0 = t * chunk;
  int s1 = s0 + chunk; if (s1 > n) s1 = n;
  int s = 0;
  for (int i = s0; i < s1; i++) s += cnt[i];
  lsum[t] = s;
  __syncthreads();
  for (int off = 1; off < 1024; off <<= 1) {
    int v = (t >= off) ? lsum[t - off] : 0;
    __syncthreads();
    lsum[t] += v;
    __syncthreads();
  }
  if (t == 0) row_ptr[n] = lsum[1023];
  int prefix = (t == 0) ? 0 : lsum[t - 1];
  for (int i = s0; i < s1; i++) {
    int c = cnt[i];
    row_ptr[i] = prefix;
    cursor[i] = prefix;
    prefix += c;
  }
}

// scatter2: build sorted-space metadata.
__global__ void gn_scatter2(const int* __restrict__ snd, const int* __restrict__ rcv,
                            int* cur_s, int* cur_r,
                            int* __restrict__ el_s, int* __restrict__ pos_s,
                            int* __restrict__ el_r2,
                            int* __restrict__ snd_srt, int* __restrict__ rcv_srt) {
  int i = blockIdx.x * 256 + threadIdx.x;
  if (i >= NE) return;
  int s = snd[i], r = rcv[i];
  int p = atomicAdd(&cur_s[s], 1);
  int q = atomicAdd(&cur_r[r], 1);
  el_s[p] = i;
  pos_s[i] = p;
  el_r2[q] = p;
  snd_srt[p] = s;
  rcv_srt[p] = r;
}

// ---------------- merged segment sums: sent (contiguous) + recv (gather), 8x ILP ----------------
__global__ void gn_segsum2(const int* __restrict__ row_s, const int* __restrict__ row_r,
                           const int* __restrict__ el_r2,
                           const u16* __restrict__ e,
                           u16* __restrict__ sent, u16* __restrict__ recv) {
  int node = blockIdx.x * 4 + (threadIdx.x >> 6);
  int w = threadIdx.x & 63;
  if (w >= 48) return;
  {
    int beg = row_s[node], end = row_s[node + 1];
    float ax[8] = {}, ay[8] = {};
    int j = beg;
    for (; j + 8 <= end; j += 8) {
      u32 v[8];
      #pragma unroll
      for (int q = 0; q < 8; q++) v[q] = ((const u32*)(e + (size_t)(j + q) * 96))[w];
      #pragma unroll
      for (int q = 0; q < 8; q++) {
        ax[q] += bf2f((u16)(v[q] & 0xffffu));
        ay[q] += bf2f((u16)(v[q] >> 16));
      }
    }
    for (; j < end; j++) {
      u32 v = ((const u32*)(e + (size_t)j * 96))[w];
      ax[0] += bf2f((u16)(v & 0xffffu)); ay[0] += bf2f((u16)(v >> 16));
    }
    float sx = ((ax[0] + ax[1]) + (ax[2] + ax[3])) + ((ax[4] + ax[5]) + (ax[6] + ax[7]));
    float sy = ((ay[0] + ay[1]) + (ay[2] + ay[3])) + ((ay[4] + ay[5]) + (ay[6] + ay[7]));
    ((u32*)(sent + (size_t)node * 96))[w] = (u32)f2bf(sx) | ((u32)f2bf(sy) << 16);
  }
  {
    int beg = row_r[node], end = row_r[node + 1];
    float ax[8] = {}, ay[8] = {};
    int j = beg;
    for (; j + 8 <= end; j += 8) {
      u32 v[8];
      #pragma unroll
      for (int q = 0; q < 8; q++) v[q] = ((const u32*)(e + (size_t)el_r2[j + q] * 96))[w];
      #pragma unroll
      for (int q = 0; q < 8; q++) {
        ax[q] += bf2f((u16)(v[q] & 0xffffu));
        ay[q] += bf2f((u16)(v[q] >> 16));
      }
    }
    for (; j < end; j++) {
      u32 v = ((const u32*)(e + (size_t)el_r2[j] * 96))[w];
      ax[0] += bf2f((u16)(v & 0xffffu)); ay[0] += bf2f((u16)(v >> 16));
    }
    float sx = ((ax[0] + ax[1]) + (ax[2] + ax[3])) + ((ax[4] + ax[5]) + (ax[6] + ax[7]));
    float sy = ((ay[0] + ay[1]) + (ay[2] + ay[3])) + ((ay[4] + ay[5]) + (ay[6] + ay[7]));
    ((u32*)(recv + (size_t)node * 96))[w] = (u32)f2bf(sx) | ((u32)f2bf(sy) << 16);
  }
}

// ---------------- column sum of bf16 [M][96] -> atomicAdd float[96] ----------------
__global__ void gn_colsum(const u16* __restrict__ x, float* __restrict__ out, int M) {
  int w = threadIdx.x & 63;
  int rg = threadIdx.x >> 6;
  if (w >= 48) return;
  float ax = 0.f, ay = 0.f;
  for (int r = blockIdx.x * 4 + rg; r < M; r += gridDim.x * 4) {
    u32 v = ((const u32*)(x + (size_t)r * 96))[w];
    ax += bf2f((u16)(v & 0xffffu));
    ay += bf2f((u16)(v >> 16));
  }
  atomicAdd(&out[2 * w], ax);
  atomicAdd(&out[2 * w + 1], ay);
}

// ---------------- per-step constant vectors: cvec = g @ W_gblock + b1 ----------------
__global__ void gn_cvec(const float* __restrict__ g, const float* __restrict__ ew1,
                        const float* __restrict__ eb1, float* __restrict__ cve,
                        const float* __restrict__ nw1, const float* __restrict__ nb1,
                        float* __restrict__ cvn, int s) {
  int f = threadIdx.x;
  if (f >= 96) return;
  const float* W = (blockIdx.x == 0 ? ew1 : nw1) + s * 36864 + 288 * 96;
  const float* b = (blockIdx.x == 0 ? eb1 : nb1) + s * 96;
  float* o = blockIdx.x == 0 ? cve : cvn;
  float a = b[f];
  for (int k = 0; k < 96; k++) a += g[k] * W[k * 96 + f];
  o[f] = a;
}

// ---------------- node projections: ps = n@ew1[96:192], pr = n@ew1[192:288] ----------------
__global__ __launch_bounds__(256) void gn_proj(const u16* __restrict__ n_in,
                                               const u16* __restrict__ wts, const u16* __restrict__ wtr,
                                               u16* __restrict__ ps, u16* __restrict__ pr) {
  __shared__ u16 WS[96][104];
  __shared__ u16 WR[96][104];
  for (int i = threadIdx.x; i < 96 * 48; i += 256) {
    int n = i / 48, k2 = (i - n * 48) * 2;
    *(u32*)&WS[n][k2] = ((const u32*)wts)[i];
    *(u32*)&WR[n][k2] = ((const u32*)wtr)[i];
  }
  __syncthreads();
  const int wave = threadIdx.x >> 6, lane = threadIdx.x & 63;
  const int l15 = lane & 15, lhi = lane >> 4;
  #pragma unroll 1
  for (int grp = 0; grp < 2; grp++) {
    const int gidx = wave * 2 + grp;
    const int ncol = blockIdx.x * 128 + gidx * 16 + l15;
    const int nc = ncol < NN ? ncol : (NN - 1);
    const u16* row = n_in + (size_t)nc * 96;
    u16x8 xf0 = *(const u16x8*)(row + 0 * 32 + lhi * 8);
    u16x8 xf1 = *(const u16x8*)(row + 1 * 32 + lhi * 8);
    u16x8 xf2 = *(const u16x8*)(row + 2 * 32 + lhi * 8);
    f32x4 a[6] = {}, b[6] = {};
    #pragma unroll
    for (int kb = 0; kb < 3; kb++) {
      u16x8 xf = (kb == 0) ? xf0 : ((kb == 1) ? xf1 : xf2);
      #pragma unroll
      for (int t = 0; t < 6; t++) {
        u16x8 wfa = *(const u16x8*)&WS[t * 16 + l15][kb * 32 + lhi * 8];
        u16x8 wfb = *(const u16x8*)&WR[t * 16 + l15][kb * 32 + lhi * 8];
        a[t] = MFMA(wfa, xf, a[t]);
        b[t] = MFMA(wfb, xf, b[t]);
      }
    }
    if (ncol < NN) {
      #pragma unroll
      for (int t = 0; t < 6; t++) {
        u16x4 ra = {f2bf(a[t][0]), f2bf(a[t][1]), f2bf(a[t][2]), f2bf(a[t][3])};
        u16x4 rb = {f2bf(b[t][0]), f2bf(b[t][1]), f2bf(b[t][2]), f2bf(b[t][3])};
        *(u16x4*)(ps + (size_t)ncol * 96 + t * 16 + lhi * 4) = ra;
        *(u16x4*)(pr + (size_t)ncol * 96 + t * 16 + lhi * 4) = rb;
      }
    }
  }
}

// ---------------- edge MLP v6: identity-MFMA gather-add, staged coalesced epilogue ----------------
#define ETPW 5
#define SB_P 104   // staged row pitch in u16 (208 B, 16-B aligned)
__global__ __launch_bounds__(512) void gn_edge6(
    u16* __restrict__ e_st,
    const u16* __restrict__ ps, const u16* __restrict__ pr,
    const int* __restrict__ snd, const int* __restrict__ rcv,   // sorted-space
    const int* __restrict__ el_s,                               // sorted pos -> orig edge
    const float* __restrict__ cvec, const float* __restrict__ b2,
    const u16* __restrict__ wf1, const u16* __restrict__ wf2,
    float* __restrict__ out32) {
  __shared__ u16 W1[1152 * 8];     // fragment-major
  __shared__ u16 W2[1152 * 8];
  __shared__ u16 Hb[8][16 * SB_P]; // per-wave scratch: H-frag region + staged tile (time-shared)
  for (int i = threadIdx.x; i < 1152; i += 512) {
    *(u16x8*)&W1[i * 8] = *(const u16x8*)(wf1 + (size_t)i * 8);
    *(u16x8*)&W2[i * 8] = *(const u16x8*)(wf2 + (size_t)i * 8);
  }
  __syncthreads();
  const int wave = threadIdx.x >> 6, lane = threadIdx.x & 63;
  const int l15 = lane & 15, lhi = lane >> 4;
  u16* myH = Hb[wave];
  const long t0 = ((long)blockIdx.x * 8 + wave) * ETPW;

  // identity A-fragments: Iev nonzero at k==m (lhi<2), Iod at k==16+m (lhi>=2); bf16(1.0)=0x3F80
  u16x8 Iev, Iod;
  #pragma unroll
  for (int j = 0; j < 8; j++) {
    Iev[j] = (lhi * 8 + j == l15) ? (u16)0x3F80 : (u16)0;
    Iod[j] = (lhi * 8 + j == 16 + l15) ? (u16)0x3F80 : (u16)0;
  }

  int r3[3], o3[3];
  #pragma unroll
  for (int s3 = 0; s3 < 3; s3++) { int g = s3 * 512 + lane * 8; r3[s3] = g / 96; o3[s3] = g - 96 * r3[s3]; }
  int r6[6], o6[6];
  #pragma unroll
  for (int s6 = 0; s6 < 6; s6++) { int g = s6 * 256 + lane * 4; r6[s6] = g / 96; o6[s6] = g - 96 * r6[s6]; }

  u16x8 xf0, xf1, xf2;
  u16x8 psf[3], prf[3];
  u16x8 nxf0, nxf1, nxf2; int nsi = 0, nri = 0;
  u16x8 npsf[3], nprf[3];

  {
    const u16* erow = e_st + (t0 * 16 + l15) * 96;
    xf0 = *(const u16x8*)(erow + lhi * 8);
    xf1 = *(const u16x8*)(erow + 32 + lhi * 8);
    xf2 = *(const u16x8*)(erow + 64 + lhi * 8);
    int si = snd[t0 * 16 + l15], ri = rcv[t0 * 16 + l15];
    const u16* pa = ps + (size_t)si * 96 + lhi * 8;
    const u16* pb = pr + (size_t)ri * 96 + lhi * 8;
    #pragma unroll
    for (int c = 0; c < 3; c++) { psf[c] = *(const u16x8*)(pa + c * 32); prf[c] = *(const u16x8*)(pb + c * 32); }
  }

  #pragma unroll 1
  for (int it = 0; it < ETPW; it++) {
    const long tb = (t0 + it) * 16;            // first edge pos of tile
    const long ecol = tb + l15;
    if (it + 1 < ETPW) {
      const u16* erow = e_st + (ecol + 16) * 96;
      nxf0 = *(const u16x8*)(erow + lhi * 8);
      nxf1 = *(const u16x8*)(erow + 32 + lhi * 8);
      nxf2 = *(const u16x8*)(erow + 64 + lhi * 8);
      nsi = snd[ecol + 16]; nri = rcv[ecol + 16];
    }
    // GEMM1 (W1) + identity gather-add MFMAs
    f32x4 acc[6] = {};
    #pragma unroll
    for (int t = 0; t < 6; t++) acc[t] = MFMA(*(const u16x8*)&W1[((t * 3 + 0) * 64 + lane) * 8], xf0, acc[t]);
    #pragma unroll
    for (int t = 0; t < 6; t++) acc[t] = MFMA(*(const u16x8*)&W1[((t * 3 + 1) * 64 + lane) * 8], xf1, acc[t]);
    #pragma unroll
    for (int t = 0; t < 6; t++) acc[t] = MFMA(*(const u16x8*)&W1[((t * 3 + 2) * 64 + lane) * 8], xf2, acc[t]);
    #pragma unroll
    for (int t = 0; t < 6; t++) {
      u16x8 ia = (t & 1) ? Iod : Iev;
      acc[t] = MFMA(ia, psf[t >> 1], acc[t]);
      acc[t] = MFMA(ia, prf[t >> 1], acc[t]);
    }
    if (it + 1 < ETPW) {
      const u16* pa = ps + (size_t)nsi * 96 + lhi * 8;
      const u16* pb = pr + (size_t)nri * 96 + lhi * 8;
      #pragma unroll
      for (int c = 0; c < 3; c++) { npsf[c] = *(const u16x8*)(pa + c * 32); nprf[c] = *(const u16x8*)(pb + c * 32); }
    }
    // guard: previous iteration's staged reads done before H-frag rewrite
    asm volatile("s_waitcnt lgkmcnt(0)" ::: "memory");
    __builtin_amdgcn_sched_barrier(0);
    // epilogue 1: + cvec, leaky-relu, write H fragment-major
    #pragma unroll
    for (int t = 0; t < 6; t++) {
      f32x4 cv = *(const f32x4*)(cvec + t * 16 + lhi * 4);
      u16x4 hp;
      #pragma unroll
      for (int j = 0; j < 4; j++) {
        float v = acc[t][j] + cv[j];
        v = v > 0.f ? v : 0.01f * v;
        hp[j] = f2bf(v);
      }
      int q = (4 * t + lhi) & 7;
      int kb2 = (4 * t + lhi) >> 3;
      *(u16x4*)&myH[(kb2 * 64 + (q >> 1) * 16 + l15) * 8 + (q & 1) * 4] = hp;
    }
    // GEMM2
    f32x4 o[6] = {};
    #pragma unroll
    for (int kb = 0; kb < 3; kb++) {
      u16x8 hf = *(const u16x8*)&myH[(kb * 64 + lane) * 8];
      #pragma unroll
      for (int t = 0; t < 6; t++)
        o[t] = MFMA(*(const u16x8*)&W2[((t * 3 + kb) * 64 + lane) * 8], hf, o[t]);
    }
    // stage bf16 tile [16][SB_P]
    asm volatile("s_waitcnt lgkmcnt(0)" ::: "memory");
    __builtin_amdgcn_sched_barrier(0);
    #pragma unroll
    for (int t = 0; t < 6; t++) {
      f32x4 bv = *(const f32x4*)(b2 + t * 16 + lhi * 4);
      f32x4 ov = o[t] + bv;
      u16x4 r4 = {f2bf(ov[0]), f2bf(ov[1]), f2bf(ov[2]), f2bf(ov[3])};
      *(u16x4*)&myH[l15 * SB_P + t * 16 + lhi * 4] = r4;
    }
    asm volatile("s_waitcnt lgkmcnt(0)" ::: "memory");
    __builtin_amdgcn_sched_barrier(0);
    // coalesced e_st store: 3 x 1KB contiguous bursts
    #pragma unroll
    for (int s3 = 0; s3 < 3; s3++) {
      u16x8 v = *(const u16x8*)&myH[r3[s3] * SB_P + o3[s3]];
      *(u16x8*)(e_st + tb * 96 + s3 * 512 + lane * 8) = v;
    }
    // out32 (last step): scatter rows to original edge order
    if (out32) {
      #pragma unroll
      for (int s6 = 0; s6 < 6; s6++) {
        long oc = el_s[tb + r6[s6]];
        u16x4 v = *(const u16x4*)&myH[r6[s6] * SB_P + o6[s6]];
        f32x4 f = {bf2f(v[0]), bf2f(v[1]), bf2f(v[2]), bf2f(v[3])};
        *(f32x4*)(out32 + oc * 96 + o6[s6]) = f;
      }
    }
    xf0 = nxf0; xf1 = nxf1; xf2 = nxf2;
    #pragma unroll
    for (int c = 0; c < 3; c++) { psf[c] = npsf[c]; prf[c] = nprf[c]; }
  }
}

// ---------------- node MLP (K=288 over n/sent/recv bf16 blocks) ----------------
__global__ __launch_bounds__(256) void gn_node(
    const u16* __restrict__ n_in, const u16* __restrict__ sent, const u16* __restrict__ recv,
    const u16* __restrict__ wta, const u16* __restrict__ wtb, const u16* __restrict__ wtc,
    const u16* __restrict__ wt2,
    const float* __restrict__ cvec, const float* __restrict__ b2,
    u16* __restrict__ n_out, float* __restrict__ out32) {
  __shared__ u16 WA[96][104];
  __shared__ u16 WB[96][104];
  __shared__ u16 Hb[4][16][104];
  for (int i = threadIdx.x; i < 96 * 48; i += 256) {
    int n = i / 48, k2 = (i - n * 48) * 2;
    *(u32*)&WA[n][k2] = ((const u32*)wta)[i];
    *(u32*)&WB[n][k2] = ((const u32*)wtb)[i];
  }
  __syncthreads();
  const int wave = threadIdx.x >> 6, lane = threadIdx.x & 63;
  const int l15 = lane & 15, lhi = lane >> 4;
  #pragma unroll 1
  for (int grp = 0; grp < 2; grp++) {
    const int gidx = wave * 2 + grp;
    const int ncol = blockIdx.x * 128 + gidx * 16 + l15;
    const int nc = ncol < NN ? ncol : (NN - 1);
    f32x4 acc[6] = {};
    {
      const u16* row = n_in + (size_t)nc * 96;
      #pragma unroll
      for (int kb = 0; kb < 3; kb++) {
        u16x8 xf = *(const u16x8*)(row + kb * 32 + lhi * 8);
        #pragma unroll
        for (int t = 0; t < 6; t++) {
          u16x8 wf = *(const u16x8*)&WA[t * 16 + l15][kb * 32 + lhi * 8];
          acc[t] = MFMA(wf, xf, acc[t]);
        }
      }
    }
    {
      const u16* row = sent + (size_t)nc * 96;
      #pragma unroll
      for (int kb = 0; kb < 3; kb++) {
        u16x8 xf = *(const u16x8*)(row + kb * 32 + lhi * 8);
        #pragma unroll
        for (int t = 0; t < 6; t++) {
          u16x8 wf = *(const u16x8*)&WB[t * 16 + l15][kb * 32 + lhi * 8];
          acc[t] = MFMA(wf, xf, acc[t]);
        }
      }
    }
    {
      const u16* row = recv + (size_t)nc * 96;
      #pragma unroll
      for (int kb = 0; kb < 3; kb++) {
        u16x8 xf = *(const u16x8*)(row + kb * 32 + lhi * 8);
        #pragma unroll
        for (int t = 0; t < 6; t++) {
          u16x8 wf = *(const u16x8*)(wtc + (t * 16 + l15) * 96 + kb * 32 + lhi * 8);
          acc[t] = MFMA(wf, xf, acc[t]);
        }
      }
    }
    #pragma unroll
    for (int t = 0; t < 6; t++) {
      f32x4 cv = *(const f32x4*)(cvec + t * 16 + lhi * 4);
      u16x4 hp;
      #pragma unroll
      for (int j = 0; j < 4; j++) {
        float v = acc[t][j] + cv[j];
        v = v > 0.f ? v : 0.01f * v;
        hp[j] = f2bf(v);
      }
      *(u16x4*)&Hb[wave][l15][t * 16 + lhi * 4] = hp;
    }
    f32x4 o[6] = {};
    #pragma unroll
    for (int kb = 0; kb < 3; kb++) {
      u16x8 hf = *(const u16x8*)&Hb[wave][l15][kb * 32 + lhi * 8];
      #pragma unroll
      for (int t = 0; t < 6; t++) {
        u16x8 wf = *(const u16x8*)(wt2 + (t * 16 + l15) * 96 + kb * 32 + lhi * 8);
        o[t] = MFMA(wf, hf, o[t]);
      }
    }
    if (ncol < NN) {
      #pragma unroll
      for (int t = 0; t < 6; t++) {
        f32x4 bv = *(const f32x4*)(b2 + t * 16 + lhi * 4);
        f32x4 ov = o[t] + bv;
        u16x4 r = {f2bf(ov[0]), f2bf(ov[1]), f2bf(ov[2]), f2bf(ov[3])};
        *(u16x4*)(n_out + (size_t)ncol * 96 + t * 16 + lhi * 4) = r;
        if (out32) *(f32x4*)(out32 + (size_t)ncol * 96 + t * 16 + lhi * 4) = ov;
      }
    }
  }
}

// ---------------- global MLP (single WG) ----------------
__global__ void gn_global(const float* __restrict__ nsum, const float* __restrict__ esum,
                          float* gbuf, const float* __restrict__ gw1, const float* __restrict__ gb1,
                          const float* __restrict__ gw2, const float* __restrict__ gb2,
                          int s, float* outg) {
  __shared__ float x[288];
  __shared__ float h[96];
  int t = threadIdx.x;
  if (t < 96) { x[t] = nsum[t]; x[96 + t] = esum[t]; x[192 + t] = gbuf[t]; }
  __syncthreads();
  if (t < 96) {
    const float* W1 = gw1 + s * 288 * 96;
    float a = gb1[s * 96 + t];
    for (int k = 0; k < 288; k++) a += x[k] * W1[k * 96 + t];
    h[t] = a > 0.f ? a : 0.01f * a;
  }
  __syncthreads();
  if (t < 96) {
    const float* W2 = gw2 + s * 9216;
    float a = gb2[s * 96 + t];
    for (int k = 0; k < 96; k++) a += h[k] * W2[k * 96 + t];
    gbuf[t] = a;
    if (outg) outg[t] = a;
  }
}

// ---------------- host ----------------
extern "C" void kernel_launch(void* const* d_in, const int* in_sizes, int n_in,
                              void* d_out, int out_size, void* d_ws, size_t ws_size,
                              hipStream_t stream) {
  (void)in_sizes; (void)n_in; (void)out_size;
  const float* nodes    = (const float*)d_in[0];
  const float* edges    = (const float*)d_in[1];
  const float* globals_ = (const float*)d_in[2];
  const int*   senders  = (const int*)d_in[3];
  const int*   receivers= (const int*)d_in[4];
  const float* Wn = (const float*)d_in[5],  *bn = (const float*)d_in[6];
  const float* We = (const float*)d_in[7],  *be = (const float*)d_in[8];
  const float* Wg = (const float*)d_in[9],  *bg = (const float*)d_in[10];
  const float* ew1 = (const float*)d_in[11], *eb1 = (const float*)d_in[12];
  const float* ew2 = (const float*)d_in[13], *eb2 = (const float*)d_in[14];
  const float* nw1 = (const float*)d_in[15], *nb1 = (const float*)d_in[16];
  const float* nw2 = (const float*)d_in[17], *nb2 = (const float*)d_in[18];
  const float* gw1 = (const float*)d_in[19], *gb1 = (const float*)d_in[20];
  const float* gw2 = (const float*)d_in[21], *gb2 = (const float*)d_in[22];

  size_t off = 0;
  char* base = (char*)d_ws;
  auto A = [&](size_t bytes) -> void* {
    void* p = base + off;
    off = (off + bytes + 255) & ~(size_t)255;
    return p;
  };
  u16* e_bf    = (u16*)A((size_t)NE * FD * 2);     // sorted edge space
  u16* n_bf    = (u16*)A((size_t)NN * FD * 2);
  u16* ps      = (u16*)A((size_t)NN * FD * 2);
  u16* pr      = (u16*)A((size_t)NN * FD * 2);
  u16* sent    = (u16*)A((size_t)NN * FD * 2);
  u16* recv    = (u16*)A((size_t)NN * FD * 2);
  u16* wt_all  = (u16*)A((size_t)6 * 3 * 9216 * 2);
  u16* wf_all  = (u16*)A((size_t)2 * 3 * 9216 * 2);
  int* row_s   = (int*)A((size_t)(NN + 1) * 4);
  int* row_r   = (int*)A((size_t)(NN + 1) * 4);
  int* el_s    = (int*)A((size_t)NE * 4);
  int* el_r2   = (int*)A((size_t)NE * 4);
  int* pos_s   = (int*)A((size_t)NE * 4);
  int* snd_srt = (int*)A((size_t)NE * 4);
  int* rcv_srt = (int*)A((size_t)NE * 4);
  int* cur_s   = (int*)A((size_t)NN * 4);
  int* cur_r   = (int*)A((size_t)NN * 4);
  float* gbuf   = (float*)A(96 * 4);
  float* cvec_e = (float*)A(96 * 4);
  float* cvec_n = (float*)A(96 * 4);
  float* sums   = (float*)A(2 * 96 * 4);  // [0:96) nsum, [96:192) esum
  if (off > ws_size) return;  // insufficient scratch: bail

  float* out_n = (float*)d_out;
  float* out_e = out_n + (size_t)NN * FD;
  float* out_g = out_n + (size_t)NN * FD + (size_t)NE * FD;

  // WT blocks: 0 ew1_send, 1 ew1_recv, 2 nw1_n, 3 nw1_sent, 4 nw1_recv, 5 nw2
  auto WT = [&](int b, int s) { return wt_all + (size_t)(b * 3 + s) * 9216; };

  gn_wprep<<<648, 256, 0, stream>>>(ew1, nw1, nw2, wt_all);
  gn_wprep_frag<<<216, 256, 0, stream>>>(ew1, ew2, wf_all);
  gn_embed_n_mfma<<<(NN + 127) / 128, 256, 0, stream>>>(nodes, Wn, bn, n_bf);
  gn_gembed<<<1, 128, 0, stream>>>(globals_, Wg, bg, gbuf);

  hipMemsetAsync(cur_s, 0, (size_t)NN * 4, stream);
  hipMemsetAsync(cur_r, 0, (size_t)NN * 4, stream);
  gn_hist<<<(NE + 255) / 256, 256, 0, stream>>>(senders, receivers, cur_s, cur_r);
  gn_scan<<<1, 1024, 0, stream>>>(cur_s, row_s, cur_s, NN);
  gn_scan<<<1, 1024, 0, stream>>>(cur_r, row_r, cur_r, NN);
  gn_scatter2<<<(NE + 255) / 256, 256, 0, stream>>>(senders, receivers, cur_s, cur_r,
                                                    el_s, pos_s, el_r2, snd_srt, rcv_srt);
  gn_embed_e_mfma<<<NE / 128, 256, 0, stream>>>(edges, We, be, pos_s, e_bf);

  const int eblocks = NE / (16 * 8 * ETPW);   // 1250 blocks: 8 waves x 5 tiles

  for (int s = 0; s < 3; s++) {
    bool last = (s == 2);
    hipMemsetAsync(sums, 0, 2 * 96 * 4, stream);
    gn_cvec<<<2, 128, 0, stream>>>(gbuf, ew1, eb1, cvec_e, nw1, nb1, cvec_n, s);
    gn_proj<<<(NN + 127) / 128, 256, 0, stream>>>(n_bf, WT(0, s), WT(1, s), ps, pr);
    gn_edge6<<<eblocks, 512, 0, stream>>>(e_bf, ps, pr, snd_srt, rcv_srt, el_s,
                                          cvec_e, eb2 + s * 96,
                                          wf_all + (size_t)s * 9216,
                                          wf_all + (size_t)(3 + s) * 9216,
                                          last ? out_e : (float*)nullptr);
    gn_segsum2<<<NN / 4, 256, 0, stream>>>(row_s, row_r, el_r2, e_bf, sent, recv);
    gn_colsum<<<256, 256, 0, stream>>>(sent, sums + 96, NN);       // esum
    gn_node<<<(NN + 127) / 128, 256, 0, stream>>>(n_bf, sent, recv,
                                                  WT(2, s), WT(3, s), WT(4, s), WT(5, s),
                                                  cvec_n, nb2 + s * 96, n_bf,
                                                  last ? out_n : (float*)nullptr);
    gn_colsum<<<256, 256, 0, stream>>>(n_bf, sums, NN);            // nsum
    gn_global<<<1, 128, 0, stream>>>(sums, sums + 96, gbuf, gw1, gb1, gw2, gb2, s,
                                     last ? out_g : (float*)nullptr);
  }
}